// Round 12
// baseline (997.856 us; speedup 1.0000x reference)
//
#include <hip/hip_runtime.h>
#include <hip/hip_bf16.h>
#include <math.h>

typedef __hip_bfloat16 bf16;

#define NTOT 2048   // N*T
#define DIM  128    // D == E1

__device__ __forceinline__ float ldE(const void* p, long idx, int isBf16) {
  return isBf16 ? __bfloat162float(((const bf16*)p)[idx]) : ((const float*)p)[idx];
}

struct P4 { const void* p[4]; };

// detect input dtype: bf16 (flag=1) vs f32 (flag=0).
__global__ void detect_k(const void* x, int* flag) {
  const bf16* hb = (const bf16*)x;
  float mx = 0.f;
  for (int i = threadIdx.x; i < 256; i += 64) {
    float v = fabsf(__bfloat162float(hb[i]));
    if (!isfinite(v)) v = 1e30f;
    mx = fmaxf(mx, v);
  }
  #pragma unroll
  for (int o = 32; o > 0; o >>= 1) mx = fmaxf(mx, __shfl_down(mx, o));
  if (threadIdx.x == 0) *flag = (mx < 100.f) ? 1 : 0;
}

__global__ void zero_k(float* p, int n) {
  int i = blockIdx.x * 256 + threadIdx.x;
  if (i < n) p[i] = 0.f;
}

// ---------------------------------------------------------------- H pipeline
// G_k[m,e] = sum_n X_k[n,m] * W1_k[n,e]     grid (128, 4), block 128
__global__ __launch_bounds__(128) void gk_mlp1(P4 X, P4 W1, float* __restrict__ G,
                                               const int* __restrict__ dflag) {
  int inBf = *dflag;
  int m = blockIdx.x, e = threadIdx.x, k = blockIdx.y;
  const void* Xp = X.p[k];
  const void* Wp = W1.p[k];
  float acc = 0.f;
  for (int n = 0; n < NTOT; ++n)
    acc += ldE(Xp, (long)n * DIM + m, inBf) * ldE(Wp, (long)n * DIM + e, inBf);
  G[(long)k * 16384 + m * DIM + e] = acc;
}

// M_k[m,e] = sum_j relu(G_k[m,j]+b1_k[j]) * W2_k[j,e] + b2_k[e]   grid (128,4)
__global__ __launch_bounds__(128) void gk_mlp2(const float* __restrict__ G, P4 B1, P4 W2, P4 B2,
                                               float* __restrict__ M, const int* __restrict__ dflag) {
  int inBf = *dflag;
  int m = blockIdx.x, e = threadIdx.x, k = blockIdx.y;
  __shared__ float a[DIM];
  a[e] = fmaxf(G[(long)k * 16384 + m * DIM + e] + ldE(B1.p[k], e, inBf), 0.f);
  __syncthreads();
  const void* Wp = W2.p[k];
  float acc = ldE(B2.p[k], e, inBf);
  for (int j = 0; j < DIM; ++j) acc += a[j] * ldE(Wp, (long)j * DIM + e, inBf);
  M[(long)k * 16384 + m * DIM + e] = acc;
}

// h=0: A_t[k,e] = sum_j M_it[k,j]*fW1[j,e]      + M_t2n[k,j]*fW1[256+j,e]
// h=1: B_n[k,e] = sum_j M_inw[k,j]*fW1[128+j,e] + M_n2t[k,j]*fW1[384+j,e]
__global__ __launch_bounds__(128) void gk_ab(const float* __restrict__ Mk, const void* __restrict__ fW1,
                                             float* __restrict__ AB, const int* __restrict__ dflag) {
  int inBf = *dflag;
  int k = blockIdx.x, e = threadIdx.x, h = blockIdx.y;
  const float* Ma = Mk + (h == 0 ? 0 : 1) * 16384;
  const float* Mb = Mk + (h == 0 ? 2 : 3) * 16384;
  int r0 = (h == 0) ? 0 : 128, r1 = (h == 0) ? 256 : 384;
  __shared__ float sa[DIM], sb[DIM];
  sa[e] = Ma[k * DIM + e];
  sb[e] = Mb[k * DIM + e];
  __syncthreads();
  float acc = 0.f;
  for (int j = 0; j < DIM; ++j)
    acc += sa[j] * ldE(fW1, (long)(r0 + j) * DIM + e, inBf)
         + sb[j] * ldE(fW1, (long)(r1 + j) * DIM + e, inBf);
  AB[(long)h * 16384 + k * DIM + e] = acc;
}

// H1[n,e] = sum_k xt[n,k]*A_t[k,e] + xn[n,k]*B_n[k,e]     grid 2048
__global__ __launch_bounds__(128) void gk_h1(const void* __restrict__ xt, const void* __restrict__ xn,
                                             const float* __restrict__ AB, float* __restrict__ H1,
                                             const int* __restrict__ dflag) {
  int inBf = *dflag;
  int n = blockIdx.x, e = threadIdx.x;
  long xr = (long)n * DIM + e;
  __shared__ float st[DIM], sn[DIM];
  st[e] = ldE(xt, xr, inBf);
  sn[e] = ldE(xn, xr, inBf);
  __syncthreads();
  float acc = 0.f;
  for (int k = 0; k < DIM; ++k)
    acc += st[k] * AB[k * DIM + e] + sn[k] * AB[16384 + k * DIM + e];
  H1[(long)n * DIM + e] = acc;
}

// Hraw[n,e] = sum_j relu(H1[n,j]+fb1[j]) * fW2[j,e] + fb2[e]     grid 2048
__global__ __launch_bounds__(128) void gk_h2(const float* __restrict__ H1, const void* __restrict__ fb1,
                                             const void* __restrict__ fW2, const void* __restrict__ fb2,
                                             float* __restrict__ Hraw, const int* __restrict__ dflag) {
  int inBf = *dflag;
  int n = blockIdx.x, e = threadIdx.x;
  __shared__ float a[DIM];
  a[e] = fmaxf(H1[(long)n * DIM + e] + ldE(fb1, e, inBf), 0.f);
  __syncthreads();
  float acc = ldE(fb2, e, inBf);
  for (int j = 0; j < DIM; ++j) acc += a[j] * ldE(fW2, (long)j * DIM + e, inBf);
  Hraw[(long)n * DIM + e] = acc;
}

// ---------------------------------------------------------------- reductions
__device__ __forceinline__ float blockSum256(float v, float* s4) {
  #pragma unroll
  for (int o = 32; o > 0; o >>= 1) v += __shfl_down(v, o);
  int t = threadIdx.x;
  if ((t & 63) == 0) s4[t >> 6] = v;
  __syncthreads();
  float r = s4[0] + s4[1] + s4[2] + s4[3];
  __syncthreads();
  return r;
}

__global__ __launch_bounds__(256) void colstats_k(const float* __restrict__ H, float* __restrict__ stats) {
  int e = blockIdx.x;
  __shared__ float sa[4], sb[4], sc[4];
  float sum = 0.f, sq = 0.f, mx = -3.4e38f;
  for (int n = threadIdx.x; n < NTOT; n += 256) {
    float v = H[(long)n * DIM + e];
    sum += v; sq += v * v; mx = fmaxf(mx, v);
  }
  #pragma unroll
  for (int o = 32; o > 0; o >>= 1) {
    sum += __shfl_down(sum, o);
    sq  += __shfl_down(sq, o);
    mx   = fmaxf(mx, __shfl_down(mx, o));
  }
  int t = threadIdx.x;
  if ((t & 63) == 0) { int w = t >> 6; sa[w] = sum; sb[w] = sq; sc[w] = mx; }
  __syncthreads();
  if (t == 0) {
    sum = sa[0]+sa[1]+sa[2]+sa[3];
    sq  = sb[0]+sb[1]+sb[2]+sb[3];
    mx  = fmaxf(fmaxf(sc[0],sc[1]), fmaxf(sc[2],sc[3]));
    float mean = sum * (1.f / NTOT);
    float var  = (sq - sum * mean) * (1.f / (NTOT - 1));
    float ia   = 1.f / (sqrtf(fmaxf(var, 0.f)) + 1e-6f);
    stats[e]         = mean;
    stats[DIM + e]   = ia;
    stats[2*DIM + e] = (mx - mean) * ia;
  }
}

__global__ __launch_bounds__(256) void softmax_k(const float* __restrict__ Hraw, const float* __restrict__ stats,
                                                 float* __restrict__ Hp, float* __restrict__ HTp,
                                                 float* __restrict__ Ecol) {
  int e = blockIdx.x;
  __shared__ float s4[4];
  float mean = stats[e], ia = stats[DIM+e], smax = stats[2*DIM+e];
  float den = 0.f;
  for (int n = threadIdx.x; n < NTOT; n += 256) {
    float s = (Hraw[(long)n*DIM + e] - mean) * ia - smax;
    den += expf(s);
  }
  den = blockSum256(den, s4);
  float logden = logf(den);
  float invden = 1.f / den;
  float ent = 0.f;
  for (int n = threadIdx.x; n < NTOT; n += 256) {
    float s = (Hraw[(long)n*DIM + e] - mean) * ia - smax;
    float pv = expf(s) * invden;
    Hp[(long)n*DIM + e]   = pv;
    HTp[(long)e*NTOT + n] = pv;
    ent += pv * (s - logden);
  }
  ent = blockSum256(ent, s4);
  if (threadIdx.x == 0) Ecol[e] = ent;
}

__global__ __launch_bounds__(256) void jsd_k(const float* __restrict__ HTp, const float* __restrict__ Ecol,
                                             float* __restrict__ g) {
  int i = blockIdx.y, j = blockIdx.x;
  if (j <= i) return;
  __shared__ float s4[4];
  const float* Pi = HTp + (long)i * NTOT;
  const float* Pj = HTp + (long)j * NTOT;
  float acc = 0.f;
  for (int n = threadIdx.x; n < NTOT; n += 256) {
    float a = Pi[n], b = Pj[n];
    float m = 0.5f * (a + b);
    acc += (a + b) * logf(fmaxf(m, 1e-38f));
  }
  acc = blockSum256(acc, s4);
  if (threadIdx.x == 0) {
    float s = Ecol[i] + Ecol[j] - acc;   // = 2*jsd[i,j]
    atomicAdd(&g[i], s);
    atomicAdd(&g[j], s);
  }
}

__global__ __launch_bounds__(128) void wvec_k(const float* __restrict__ g, float* __restrict__ w) {
  __shared__ float s2[2];
  int t = threadIdx.x;
  float jm = g[t] * (1.0f / 256.0f);   // (2*rowsum)/2/128
  float v = jm;
  #pragma unroll
  for (int o = 32; o > 0; o >>= 1) v += __shfl_down(v, o);
  if ((t & 63) == 0) s2[t >> 6] = v;
  __syncthreads();
  float mean = (s2[0] + s2[1]) * (1.0f / 128.0f);
  __syncthreads();
  float d = jm - mean;
  v = d * d;
  #pragma unroll
  for (int o = 32; o > 0; o >>= 1) v += __shfl_down(v, o);
  if ((t & 63) == 0) s2[t >> 6] = v;
  __syncthreads();
  float var = (s2[0] + s2[1]) * (1.0f / 127.0f);
  float njm = d / (sqrtf(var) + 1e-6f);
  __syncthreads();
  v = njm;
  #pragma unroll
  for (int o = 32; o > 0; o >>= 1) v = fmaxf(v, __shfl_down(v, o));
  if ((t & 63) == 0) s2[t >> 6] = v;
  __syncthreads();
  float mx = fmaxf(s2[0], s2[1]);
  float ex = expf(njm - mx);
  __syncthreads();
  v = ex;
  #pragma unroll
  for (int o = 32; o > 0; o >>= 1) v += __shfl_down(v, o);
  if ((t & 63) == 0) s2[t >> 6] = v;
  __syncthreads();
  w[t] = ex / (s2[0] + s2[1]);
}

// ---------------------------------------------------------------- final chains
// y[n][d] = sum_k x[n][k] * theta[k][d]
__global__ __launch_bounds__(128) void yk(const void* __restrict__ x, const void* __restrict__ theta,
                                          float* __restrict__ y, const int* __restrict__ dflag) {
  int inBf = *dflag;
  int n = blockIdx.x, d = threadIdx.x;
  __shared__ float xs[DIM];
  xs[d] = ldE(x, (long)n * DIM + d, inBf);
  __syncthreads();
  float acc = 0.f;
  #pragma unroll 8
  for (int k = 0; k < DIM; ++k) acc += xs[k] * ldE(theta, (long)k * DIM + d, inBf);
  y[(long)n * DIM + d] = acc;
}

// zw[e][d] = w[e] * sum_n Hsoft[n,e] y[n][d]
__global__ __launch_bounds__(128) void zk(const float* __restrict__ HTp, const float* __restrict__ y,
                                          const float* __restrict__ w, float* __restrict__ zw) {
  int e = blockIdx.x, d = threadIdx.x;
  const float* He = HTp + (long)e * NTOT;
  float acc = 0.f;
  for (int n = 0; n < NTOT; ++n) acc += He[n] * y[(long)n * DIM + d];
  zw[(long)e * DIM + d] = acc * w[e];
}

// out[n][d] = x[n][d] + elu( sum_e Hsoft[n,e] zw[e][d] )   (f32 output)
__global__ __launch_bounds__(128) void uk(const float* __restrict__ Hp, const float* __restrict__ zw,
                                          const void* __restrict__ x, float* __restrict__ out,
                                          const int* __restrict__ dflag) {
  int inBf = *dflag;
  int n = blockIdx.x, d = threadIdx.x;
  __shared__ float hs[DIM];
  hs[d] = Hp[(long)n * DIM + d];
  __syncthreads();
  float acc = 0.f;
  #pragma unroll 8
  for (int e = 0; e < DIM; ++e) acc += hs[e] * zw[(long)e * DIM + d];
  float xv = ldE(x, (long)n * DIM + d, inBf);
  float el = acc > 0.f ? acc : expm1f(acc);
  out[(long)n * DIM + d] = xv + el;
}

// ---------------------------------------------------------------- launcher
extern "C" void kernel_launch(void* const* d_in, const int* in_sizes, int n_in,
                              void* d_out, int out_size, void* d_ws, size_t ws_size,
                              hipStream_t stream) {
  const void* xt = d_in[0];   // x_time
  const void* xn = d_in[1];   // x_news
  const void *W1[4], *b1[4], *W2[4], *b2[4];
  for (int k = 0; k < 4; ++k) {           // it, inw, t2n, n2t
    W1[k] = d_in[2 + 4*k];
    b1[k] = d_in[3 + 4*k];
    W2[k] = d_in[4 + 4*k];
    b2[k] = d_in[5 + 4*k];
  }
  const void* fW1 = d_in[18];
  const void* fb1 = d_in[19];
  const void* fW2 = d_in[20];
  const void* fb2 = d_in[21];
  const void* thT = d_in[22];
  const void* thN = d_in[23];

  // ws map (floats), peak 1245184 = 4.98 MB
  float* ws    = (float*)d_ws;
  int*   Flag  = (int*)ws;            // [0,128)
  float* Gacc  = ws + 128;            // [128,256)
  float* stats = ws + 256;            // [256,768) mean|ia|smax|Ecol
  float* Ecol  = stats + 3*DIM;
  float* Wv    = ws + 768;            // [768,896)
  float* Z     = ws + 1024;           // [1024,17408)
  float* G     = ws + 32768;          // [32768,98304)
  float* Mk    = ws + 98304;          // [98304,163840)
  float* AB    = ws + 163840;         // [163840,196608)
  float* H1    = ws + 196608;         // [196608,458752) -> Hp after softmax
  float* Hp    = H1;
  float* Hraw  = ws + 458752;         // [458752,720896)
  float* HTp   = ws + 720896;         // [720896,983040)
  float* Y     = ws + 983040;         // [983040,1245184)

  float* out0 = (float*)d_out;                 // time half (f32 output buffer)
  float* out1 = (float*)d_out + NTOT * DIM;    // news half

  detect_k<<<1, 64, 0, stream>>>(xt, Flag);
  zero_k<<<1, 256, 0, stream>>>(Gacc, 128);

  P4 Xs  = {{xt, xn, xn, xt}};
  P4 W1s = {{W1[0], W1[1], W1[2], W1[3]}};
  P4 B1s = {{b1[0], b1[1], b1[2], b1[3]}};
  P4 W2s = {{W2[0], W2[1], W2[2], W2[3]}};
  P4 B2s = {{b2[0], b2[1], b2[2], b2[3]}};

  gk_mlp1<<<dim3(128, 4), 128, 0, stream>>>(Xs, W1s, G, Flag);
  gk_mlp2<<<dim3(128, 4), 128, 0, stream>>>(G, B1s, W2s, B2s, Mk, Flag);
  gk_ab  <<<dim3(128, 2), 128, 0, stream>>>(Mk, fW1, AB, Flag);
  gk_h1  <<<NTOT, 128, 0, stream>>>(xt, xn, AB, H1, Flag);
  gk_h2  <<<NTOT, 128, 0, stream>>>(H1, fb1, fW2, fb2, Hraw, Flag);

  colstats_k<<<DIM, 256, 0, stream>>>(Hraw, stats);
  softmax_k<<<DIM, 256, 0, stream>>>(Hraw, stats, Hp, HTp, Ecol);

  jsd_k<<<dim3(DIM, DIM), 256, 0, stream>>>(HTp, Ecol, Gacc);
  wvec_k<<<1, 128, 0, stream>>>(Gacc, Wv);

  // out0 = time half: softmax-H conv (passed round 10 — unchanged)
  yk<<<NTOT, 128, 0, stream>>>(xt, thT, Y, Flag);
  zk<<<DIM, 128, 0, stream>>>(HTp, Y, Wv, Z);
  uk<<<NTOT, 128, 0, stream>>>(Hp, Z, xt, out0, Flag);

  // out1 = news half: softmax-H conv (faithful listed reference = np ref)
  yk<<<NTOT, 128, 0, stream>>>(xn, thN, Y, Flag);
  zk<<<DIM, 128, 0, stream>>>(HTp, Y, Wv, Z);
  uk<<<NTOT, 128, 0, stream>>>(Hp, Z, xn, out1, Flag);

  (void)in_sizes; (void)n_in; (void)out_size; (void)ws_size;
}

// Round 13
// 340.858 us; speedup vs baseline: 2.9275x; 2.9275x over previous
//
#include <hip/hip_runtime.h>
#include <hip/hip_bf16.h>
#include <math.h>

typedef __hip_bfloat16 bf16;

#define NTOT 2048   // N*T
#define DIM  128    // D == E1
#define MSPLIT 8    // split-K for gk_mlp1t
#define ZSPLIT 8    // split-K for zk2

__device__ __forceinline__ float ldE(const void* p, long idx, int isBf16) {
  return isBf16 ? __bfloat162float(((const bf16*)p)[idx]) : ((const float*)p)[idx];
}

struct P4 { const void* p[4]; };

// detect input dtype: bf16 (flag=1) vs f32 (flag=0).
__global__ void detect_k(const void* x, int* flag) {
  const bf16* hb = (const bf16*)x;
  float mx = 0.f;
  for (int i = threadIdx.x; i < 256; i += 64) {
    float v = fabsf(__bfloat162float(hb[i]));
    if (!isfinite(v)) v = 1e30f;
    mx = fmaxf(mx, v);
  }
  #pragma unroll
  for (int o = 32; o > 0; o >>= 1) mx = fmaxf(mx, __shfl_down(mx, o));
  if (threadIdx.x == 0) *flag = (mx < 100.f) ? 1 : 0;
}

__global__ void zero_k(float* p, int n) {
  int i = blockIdx.x * 256 + threadIdx.x;
  if (i < n) p[i] = 0.f;
}

// ---------------------------------------------------------------- H pipeline
// G_k = X_k^T @ W1_k  (tiled split-K, atomic accumulate into zeroed G)
// grid (16 tiles = 4x4, MSPLIT, 4 k), block 256
__global__ __launch_bounds__(256) void gk_mlp1t(P4 X, P4 W1, float* __restrict__ G,
                                                const int* __restrict__ dflag) {
  int inBf = *dflag;
  int k = blockIdx.z;
  int m0 = (blockIdx.x & 3) * 32;
  int e0 = (blockIdx.x >> 2) * 32;
  int n0 = blockIdx.y * (NTOT / MSPLIT);
  const void* Xp = X.p[k];
  const void* Wp = W1.p[k];
  __shared__ float Xs[32][33], Ws[32][33];
  int tid = threadIdx.x;
  int col = tid & 31;
  int row = tid >> 5;            // 0..7
  int tx = tid & 15, ty = tid >> 4;
  float a00 = 0.f, a01 = 0.f, a10 = 0.f, a11 = 0.f;
  for (int nb = 0; nb < NTOT / MSPLIT; nb += 32) {
    #pragma unroll
    for (int r = 0; r < 4; ++r) {
      int nn = row + r * 8;
      long gn = (long)(n0 + nb + nn) * DIM;
      Xs[nn][col] = ldE(Xp, gn + m0 + col, inBf);
      Ws[nn][col] = ldE(Wp, gn + e0 + col, inBf);
    }
    __syncthreads();
    #pragma unroll
    for (int nn = 0; nn < 32; ++nn) {
      float x0 = Xs[nn][2*ty], x1 = Xs[nn][2*ty+1];
      float w0 = Ws[nn][2*tx], w1 = Ws[nn][2*tx+1];
      a00 += x0 * w0; a01 += x0 * w1;
      a10 += x1 * w0; a11 += x1 * w1;
    }
    __syncthreads();
  }
  float* Gk = G + (long)k * 16384;
  int m = m0 + 2 * ty, e = e0 + 2 * tx;
  atomicAdd(&Gk[m * DIM + e],           a00);
  atomicAdd(&Gk[m * DIM + e + 1],       a01);
  atomicAdd(&Gk[(m + 1) * DIM + e],     a10);
  atomicAdd(&Gk[(m + 1) * DIM + e + 1], a11);
}

// M_k[m,e] = sum_j relu(G_k[m,j]+b1_k[j]) * W2_k[j,e] + b2_k[e]   grid (128,4)
__global__ __launch_bounds__(128) void gk_mlp2(const float* __restrict__ G, P4 B1, P4 W2, P4 B2,
                                               float* __restrict__ M, const int* __restrict__ dflag) {
  int inBf = *dflag;
  int m = blockIdx.x, e = threadIdx.x, k = blockIdx.y;
  __shared__ float a[DIM];
  a[e] = fmaxf(G[(long)k * 16384 + m * DIM + e] + ldE(B1.p[k], e, inBf), 0.f);
  __syncthreads();
  const void* Wp = W2.p[k];
  float acc = ldE(B2.p[k], e, inBf);
  for (int j = 0; j < DIM; ++j) acc += a[j] * ldE(Wp, (long)j * DIM + e, inBf);
  M[(long)k * 16384 + m * DIM + e] = acc;
}

// h=0: A_t[k,e] = sum_j M_it[k,j]*fW1[j,e]      + M_t2n[k,j]*fW1[256+j,e]
// h=1: B_n[k,e] = sum_j M_inw[k,j]*fW1[128+j,e] + M_n2t[k,j]*fW1[384+j,e]
__global__ __launch_bounds__(128) void gk_ab(const float* __restrict__ Mk, const void* __restrict__ fW1,
                                             float* __restrict__ AB, const int* __restrict__ dflag) {
  int inBf = *dflag;
  int k = blockIdx.x, e = threadIdx.x, h = blockIdx.y;
  const float* Ma = Mk + (h == 0 ? 0 : 1) * 16384;
  const float* Mb = Mk + (h == 0 ? 2 : 3) * 16384;
  int r0 = (h == 0) ? 0 : 128, r1 = (h == 0) ? 256 : 384;
  __shared__ float sa[DIM], sb[DIM];
  sa[e] = Ma[k * DIM + e];
  sb[e] = Mb[k * DIM + e];
  __syncthreads();
  float acc = 0.f;
  for (int j = 0; j < DIM; ++j)
    acc += sa[j] * ldE(fW1, (long)(r0 + j) * DIM + e, inBf)
         + sb[j] * ldE(fW1, (long)(r1 + j) * DIM + e, inBf);
  AB[(long)h * 16384 + k * DIM + e] = acc;
}

// H1[n,e] = sum_k xt[n,k]*A_t[k,e] + xn[n,k]*B_n[k,e]     grid 2048
__global__ __launch_bounds__(128) void gk_h1(const void* __restrict__ xt, const void* __restrict__ xn,
                                             const float* __restrict__ AB, float* __restrict__ H1,
                                             const int* __restrict__ dflag) {
  int inBf = *dflag;
  int n = blockIdx.x, e = threadIdx.x;
  long xr = (long)n * DIM + e;
  __shared__ float st[DIM], sn[DIM];
  st[e] = ldE(xt, xr, inBf);
  sn[e] = ldE(xn, xr, inBf);
  __syncthreads();
  float acc = 0.f;
  for (int k = 0; k < DIM; ++k)
    acc += st[k] * AB[k * DIM + e] + sn[k] * AB[16384 + k * DIM + e];
  H1[(long)n * DIM + e] = acc;
}

// Hraw[n,e] = sum_j relu(H1[n,j]+fb1[j]) * fW2[j,e] + fb2[e]     grid 2048
__global__ __launch_bounds__(128) void gk_h2(const float* __restrict__ H1, const void* __restrict__ fb1,
                                             const void* __restrict__ fW2, const void* __restrict__ fb2,
                                             float* __restrict__ Hraw, const int* __restrict__ dflag) {
  int inBf = *dflag;
  int n = blockIdx.x, e = threadIdx.x;
  __shared__ float a[DIM];
  a[e] = fmaxf(H1[(long)n * DIM + e] + ldE(fb1, e, inBf), 0.f);
  __syncthreads();
  float acc = ldE(fb2, e, inBf);
  for (int j = 0; j < DIM; ++j) acc += a[j] * ldE(fW2, (long)j * DIM + e, inBf);
  Hraw[(long)n * DIM + e] = acc;
}

// ---------------------------------------------------------------- reductions
__device__ __forceinline__ float blockSum256(float v, float* s4) {
  #pragma unroll
  for (int o = 32; o > 0; o >>= 1) v += __shfl_down(v, o);
  int t = threadIdx.x;
  if ((t & 63) == 0) s4[t >> 6] = v;
  __syncthreads();
  float r = s4[0] + s4[1] + s4[2] + s4[3];
  __syncthreads();
  return r;
}

__global__ __launch_bounds__(256) void colstats_k(const float* __restrict__ H, float* __restrict__ stats) {
  int e = blockIdx.x;
  __shared__ float sa[4], sb[4], sc[4];
  float sum = 0.f, sq = 0.f, mx = -3.4e38f;
  for (int n = threadIdx.x; n < NTOT; n += 256) {
    float v = H[(long)n * DIM + e];
    sum += v; sq += v * v; mx = fmaxf(mx, v);
  }
  #pragma unroll
  for (int o = 32; o > 0; o >>= 1) {
    sum += __shfl_down(sum, o);
    sq  += __shfl_down(sq, o);
    mx   = fmaxf(mx, __shfl_down(mx, o));
  }
  int t = threadIdx.x;
  if ((t & 63) == 0) { int w = t >> 6; sa[w] = sum; sb[w] = sq; sc[w] = mx; }
  __syncthreads();
  if (t == 0) {
    sum = sa[0]+sa[1]+sa[2]+sa[3];
    sq  = sb[0]+sb[1]+sb[2]+sb[3];
    mx  = fmaxf(fmaxf(sc[0],sc[1]), fmaxf(sc[2],sc[3]));
    float mean = sum * (1.f / NTOT);
    float var  = (sq - sum * mean) * (1.f / (NTOT - 1));
    float ia   = 1.f / (sqrtf(fmaxf(var, 0.f)) + 1e-6f);
    stats[e]         = mean;
    stats[DIM + e]   = ia;
    stats[2*DIM + e] = (mx - mean) * ia;
  }
}

__global__ __launch_bounds__(256) void softmax_k(const float* __restrict__ Hraw, const float* __restrict__ stats,
                                                 float* __restrict__ Hp, float* __restrict__ HTp,
                                                 float* __restrict__ Ecol) {
  int e = blockIdx.x;
  __shared__ float s4[4];
  float mean = stats[e], ia = stats[DIM+e], smax = stats[2*DIM+e];
  float den = 0.f;
  for (int n = threadIdx.x; n < NTOT; n += 256) {
    float s = (Hraw[(long)n*DIM + e] - mean) * ia - smax;
    den += expf(s);
  }
  den = blockSum256(den, s4);
  float logden = logf(den);
  float invden = 1.f / den;
  float ent = 0.f;
  for (int n = threadIdx.x; n < NTOT; n += 256) {
    float s = (Hraw[(long)n*DIM + e] - mean) * ia - smax;
    float pv = expf(s) * invden;
    Hp[(long)n*DIM + e]   = pv;
    HTp[(long)e*NTOT + n] = pv;
    ent += pv * (s - logden);
  }
  ent = blockSum256(ent, s4);
  if (threadIdx.x == 0) Ecol[e] = ent;
}

__global__ __launch_bounds__(256) void jsd_k(const float* __restrict__ HTp, const float* __restrict__ Ecol,
                                             float* __restrict__ g) {
  int i = blockIdx.y, j = blockIdx.x;
  if (j <= i) return;
  __shared__ float s4[4];
  const float* Pi = HTp + (long)i * NTOT;
  const float* Pj = HTp + (long)j * NTOT;
  float acc = 0.f;
  for (int n = threadIdx.x; n < NTOT; n += 256) {
    float a = Pi[n], b = Pj[n];
    float m = 0.5f * (a + b);
    acc += (a + b) * logf(fmaxf(m, 1e-38f));
  }
  acc = blockSum256(acc, s4);
  if (threadIdx.x == 0) {
    float s = Ecol[i] + Ecol[j] - acc;   // = 2*jsd[i,j]
    atomicAdd(&g[i], s);
    atomicAdd(&g[j], s);
  }
}

__global__ __launch_bounds__(128) void wvec_k(const float* __restrict__ g, float* __restrict__ w) {
  __shared__ float s2[2];
  int t = threadIdx.x;
  float jm = g[t] * (1.0f / 256.0f);   // (2*rowsum)/2/128
  float v = jm;
  #pragma unroll
  for (int o = 32; o > 0; o >>= 1) v += __shfl_down(v, o);
  if ((t & 63) == 0) s2[t >> 6] = v;
  __syncthreads();
  float mean = (s2[0] + s2[1]) * (1.0f / 128.0f);
  __syncthreads();
  float d = jm - mean;
  v = d * d;
  #pragma unroll
  for (int o = 32; o > 0; o >>= 1) v += __shfl_down(v, o);
  if ((t & 63) == 0) s2[t >> 6] = v;
  __syncthreads();
  float var = (s2[0] + s2[1]) * (1.0f / 127.0f);
  float njm = d / (sqrtf(var) + 1e-6f);
  __syncthreads();
  v = njm;
  #pragma unroll
  for (int o = 32; o > 0; o >>= 1) v = fmaxf(v, __shfl_down(v, o));
  if ((t & 63) == 0) s2[t >> 6] = v;
  __syncthreads();
  float mx = fmaxf(s2[0], s2[1]);
  float ex = expf(njm - mx);
  __syncthreads();
  v = ex;
  #pragma unroll
  for (int o = 32; o > 0; o >>= 1) v += __shfl_down(v, o);
  if ((t & 63) == 0) s2[t >> 6] = v;
  __syncthreads();
  w[t] = ex / (s2[0] + s2[1]);
}

// ---------------------------------------------------------------- final chains
// y[n][d] = sum_k x[n][k] * theta[k][d]
__global__ __launch_bounds__(128) void yk(const void* __restrict__ x, const void* __restrict__ theta,
                                          float* __restrict__ y, const int* __restrict__ dflag) {
  int inBf = *dflag;
  int n = blockIdx.x, d = threadIdx.x;
  __shared__ float xs[DIM];
  xs[d] = ldE(x, (long)n * DIM + d, inBf);
  __syncthreads();
  float acc = 0.f;
  #pragma unroll 8
  for (int k = 0; k < DIM; ++k) acc += xs[k] * ldE(theta, (long)k * DIM + d, inBf);
  y[(long)n * DIM + d] = acc;
}

// split-K: zw[e][d] += w[e] * sum_{n in split} Hsoft[n,e] y[n][d]   grid (128, ZSPLIT)
__global__ __launch_bounds__(128) void zk2(const float* __restrict__ HTp, const float* __restrict__ y,
                                           const float* __restrict__ w, float* __restrict__ zw) {
  int e = blockIdx.x, d = threadIdx.x, s = blockIdx.y;
  const float* He = HTp + (long)e * NTOT + s * (NTOT / ZSPLIT);
  const float* yp = y + (long)s * (NTOT / ZSPLIT) * DIM + d;
  float acc = 0.f;
  for (int n = 0; n < NTOT / ZSPLIT; ++n) acc += He[n] * yp[(long)n * DIM];
  atomicAdd(&zw[(long)e * DIM + d], acc * w[e]);
}

// out[n][d] = x[n][d] + elu( sum_e Hsoft[n,e] zw[e][d] )   (f32 output)
__global__ __launch_bounds__(128) void uk(const float* __restrict__ Hp, const float* __restrict__ zw,
                                          const void* __restrict__ x, float* __restrict__ out,
                                          const int* __restrict__ dflag) {
  int inBf = *dflag;
  int n = blockIdx.x, d = threadIdx.x;
  __shared__ float hs[DIM];
  hs[d] = Hp[(long)n * DIM + d];
  __syncthreads();
  float acc = 0.f;
  #pragma unroll 8
  for (int e = 0; e < DIM; ++e) acc += hs[e] * zw[(long)e * DIM + d];
  float xv = ldE(x, (long)n * DIM + d, inBf);
  float el = acc > 0.f ? acc : expm1f(acc);
  out[(long)n * DIM + d] = xv + el;
}

// ---------------------------------------------------------------- launcher
extern "C" void kernel_launch(void* const* d_in, const int* in_sizes, int n_in,
                              void* d_out, int out_size, void* d_ws, size_t ws_size,
                              hipStream_t stream) {
  const void* xt = d_in[0];   // x_time
  const void* xn = d_in[1];   // x_news
  const void *W1[4], *b1[4], *W2[4], *b2[4];
  for (int k = 0; k < 4; ++k) {           // it, inw, t2n, n2t
    W1[k] = d_in[2 + 4*k];
    b1[k] = d_in[3 + 4*k];
    W2[k] = d_in[4 + 4*k];
    b2[k] = d_in[5 + 4*k];
  }
  const void* fW1 = d_in[18];
  const void* fb1 = d_in[19];
  const void* fW2 = d_in[20];
  const void* fb2 = d_in[21];
  const void* thT = d_in[22];
  const void* thN = d_in[23];

  // ws map (floats), peak 1246208 = 4.98 MB
  float* ws    = (float*)d_ws;
  int*   Flag  = (int*)ws;            // [0,128)
  float* Gacc  = ws + 128;            // [128,256)    zeroed
  float* stats = ws + 256;            // [256,768)    mean|ia|smax|Ecol
  float* Ecol  = stats + 3*DIM;
  float* Wv    = ws + 768;            // [768,896)
  float* Z     = ws + 1024;           // [1024,17408)   zeroed (zk2 out0)
  float* Z2    = ws + 17408;          // [17408,33792)  zeroed (zk2 out1)
  float* G     = ws + 33792;          // [33792,99328)  zeroed (gk_mlp1t atomic)
  float* Mk    = ws + 99328;          // [99328,164864)
  float* AB    = ws + 164864;         // [164864,197632)
  float* H1    = ws + 197632;         // [197632,459776) -> Hp after softmax
  float* Hp    = H1;
  float* Hraw  = ws + 459776;         // [459776,721920)
  float* HTp   = ws + 721920;         // [721920,984064)
  float* Y     = ws + 984064;         // [984064,1246208)

  float* out0 = (float*)d_out;                 // time half (f32 output buffer)
  float* out1 = (float*)d_out + NTOT * DIM;    // news half

  detect_k<<<1, 64, 0, stream>>>(xt, Flag);
  // zero Gacc..G end: [128, 99328) = 99200 floats (covers Gacc, Z, Z2, G)
  zero_k<<<(99200 + 255) / 256, 256, 0, stream>>>(ws + 128, 99200);

  P4 Xs  = {{xt, xn, xn, xt}};
  P4 W1s = {{W1[0], W1[1], W1[2], W1[3]}};
  P4 B1s = {{b1[0], b1[1], b1[2], b1[3]}};
  P4 W2s = {{W2[0], W2[1], W2[2], W2[3]}};
  P4 B2s = {{b2[0], b2[1], b2[2], b2[3]}};

  gk_mlp1t<<<dim3(16, MSPLIT, 4), 256, 0, stream>>>(Xs, W1s, G, Flag);
  gk_mlp2<<<dim3(128, 4), 128, 0, stream>>>(G, B1s, W2s, B2s, Mk, Flag);
  gk_ab  <<<dim3(128, 2), 128, 0, stream>>>(Mk, fW1, AB, Flag);
  gk_h1  <<<NTOT, 128, 0, stream>>>(xt, xn, AB, H1, Flag);
  gk_h2  <<<NTOT, 128, 0, stream>>>(H1, fb1, fW2, fb2, Hraw, Flag);

  colstats_k<<<DIM, 256, 0, stream>>>(Hraw, stats);
  softmax_k<<<DIM, 256, 0, stream>>>(Hraw, stats, Hp, HTp, Ecol);

  jsd_k<<<dim3(DIM, DIM), 256, 0, stream>>>(HTp, Ecol, Gacc);
  wvec_k<<<1, 128, 0, stream>>>(Gacc, Wv);

  // out0 = time half
  yk<<<NTOT, 128, 0, stream>>>(xt, thT, Y, Flag);
  zk2<<<dim3(DIM, ZSPLIT), 128, 0, stream>>>(HTp, Y, Wv, Z);
  uk<<<NTOT, 128, 0, stream>>>(Hp, Z, xt, out0, Flag);

  // out1 = news half
  yk<<<NTOT, 128, 0, stream>>>(xn, thN, Y, Flag);
  zk2<<<dim3(DIM, ZSPLIT), 128, 0, stream>>>(HTp, Y, Wv, Z2);
  uk<<<NTOT, 128, 0, stream>>>(Hp, Z2, xn, out1, Flag);

  (void)in_sizes; (void)n_in; (void)out_size; (void)ws_size;
}

// Round 14
// 247.719 us; speedup vs baseline: 4.0282x; 1.3760x over previous
//
#include <hip/hip_runtime.h>
#include <hip/hip_bf16.h>
#include <math.h>

typedef __hip_bfloat16 bf16;

#define NTOT 2048   // N*T
#define DIM  128    // D == E1
#define MSPLIT 8    // split-K for gk_mlp1t
#define ZSPLIT 8    // split-K for xz_k
#define JT 16       // jsd tile width (columns)
#define JNC 128     // jsd n-chunk in LDS
#define JNSPLIT 8   // jsd n splits

__device__ __forceinline__ float ldE(const void* p, long idx, int isBf16) {
  return isBf16 ? __bfloat162float(((const bf16*)p)[idx]) : ((const float*)p)[idx];
}

struct P4 { const void* p[4]; };

// detect input dtype: bf16 (flag=1) vs f32 (flag=0).
__global__ void detect_k(const void* x, int* flag) {
  const bf16* hb = (const bf16*)x;
  float mx = 0.f;
  for (int i = threadIdx.x; i < 256; i += 64) {
    float v = fabsf(__bfloat162float(hb[i]));
    if (!isfinite(v)) v = 1e30f;
    mx = fmaxf(mx, v);
  }
  #pragma unroll
  for (int o = 32; o > 0; o >>= 1) mx = fmaxf(mx, __shfl_down(mx, o));
  if (threadIdx.x == 0) *flag = (mx < 100.f) ? 1 : 0;
}

__global__ void zero_k(float* p, int n) {
  int i = blockIdx.x * 256 + threadIdx.x;
  if (i < n) p[i] = 0.f;
}

// ---------------------------------------------------------------- H pipeline
// G_k = X_k^T @ W1_k  (tiled split-K, atomic accumulate into zeroed G)
__global__ __launch_bounds__(256) void gk_mlp1t(P4 X, P4 W1, float* __restrict__ G,
                                                const int* __restrict__ dflag) {
  int inBf = *dflag;
  int k = blockIdx.z;
  int m0 = (blockIdx.x & 3) * 32;
  int e0 = (blockIdx.x >> 2) * 32;
  int n0 = blockIdx.y * (NTOT / MSPLIT);
  const void* Xp = X.p[k];
  const void* Wp = W1.p[k];
  __shared__ float Xs[32][33], Ws[32][33];
  int tid = threadIdx.x;
  int col = tid & 31;
  int row = tid >> 5;
  int tx = tid & 15, ty = tid >> 4;
  float a00 = 0.f, a01 = 0.f, a10 = 0.f, a11 = 0.f;
  for (int nb = 0; nb < NTOT / MSPLIT; nb += 32) {
    #pragma unroll
    for (int r = 0; r < 4; ++r) {
      int nn = row + r * 8;
      long gn = (long)(n0 + nb + nn) * DIM;
      Xs[nn][col] = ldE(Xp, gn + m0 + col, inBf);
      Ws[nn][col] = ldE(Wp, gn + e0 + col, inBf);
    }
    __syncthreads();
    #pragma unroll
    for (int nn = 0; nn < 32; ++nn) {
      float x0 = Xs[nn][2*ty], x1 = Xs[nn][2*ty+1];
      float w0 = Ws[nn][2*tx], w1 = Ws[nn][2*tx+1];
      a00 += x0 * w0; a01 += x0 * w1;
      a10 += x1 * w0; a11 += x1 * w1;
    }
    __syncthreads();
  }
  float* Gk = G + (long)k * 16384;
  int m = m0 + 2 * ty, e = e0 + 2 * tx;
  atomicAdd(&Gk[m * DIM + e],           a00);
  atomicAdd(&Gk[m * DIM + e + 1],       a01);
  atomicAdd(&Gk[(m + 1) * DIM + e],     a10);
  atomicAdd(&Gk[(m + 1) * DIM + e + 1], a11);
}

// M_k[m,e] = sum_j relu(G_k[m,j]+b1_k[j]) * W2_k[j,e] + b2_k[e]   grid (128,4)
__global__ __launch_bounds__(128) void gk_mlp2(const float* __restrict__ G, P4 B1, P4 W2, P4 B2,
                                               float* __restrict__ M, const int* __restrict__ dflag) {
  int inBf = *dflag;
  int m = blockIdx.x, e = threadIdx.x, k = blockIdx.y;
  __shared__ float a[DIM];
  a[e] = fmaxf(G[(long)k * 16384 + m * DIM + e] + ldE(B1.p[k], e, inBf), 0.f);
  __syncthreads();
  const void* Wp = W2.p[k];
  float acc = ldE(B2.p[k], e, inBf);
  #pragma unroll 8
  for (int j = 0; j < DIM; ++j) acc += a[j] * ldE(Wp, (long)j * DIM + e, inBf);
  M[(long)k * 16384 + m * DIM + e] = acc;
}

// h=0: A_t[k,e] = sum_j M_it[k,j]*fW1[j,e]      + M_t2n[k,j]*fW1[256+j,e]
// h=1: B_n[k,e] = sum_j M_inw[k,j]*fW1[128+j,e] + M_n2t[k,j]*fW1[384+j,e]
__global__ __launch_bounds__(128) void gk_ab(const float* __restrict__ Mk, const void* __restrict__ fW1,
                                             float* __restrict__ AB, const int* __restrict__ dflag) {
  int inBf = *dflag;
  int k = blockIdx.x, e = threadIdx.x, h = blockIdx.y;
  const float* Ma = Mk + (h == 0 ? 0 : 1) * 16384;
  const float* Mb = Mk + (h == 0 ? 2 : 3) * 16384;
  int r0 = (h == 0) ? 0 : 128, r1 = (h == 0) ? 256 : 384;
  __shared__ float sa[DIM], sb[DIM];
  sa[e] = Ma[k * DIM + e];
  sb[e] = Mb[k * DIM + e];
  __syncthreads();
  float acc = 0.f;
  #pragma unroll 8
  for (int j = 0; j < DIM; ++j)
    acc += sa[j] * ldE(fW1, (long)(r0 + j) * DIM + e, inBf)
         + sb[j] * ldE(fW1, (long)(r1 + j) * DIM + e, inBf);
  AB[(long)h * 16384 + k * DIM + e] = acc;
}

// H1[n,e] = sum_k xt[n,k]*A_t[k,e] + xn[n,k]*B_n[k,e]     grid 2048
__global__ __launch_bounds__(128) void gk_h1(const void* __restrict__ xt, const void* __restrict__ xn,
                                             const float* __restrict__ AB, float* __restrict__ H1,
                                             const int* __restrict__ dflag) {
  int inBf = *dflag;
  int n = blockIdx.x, e = threadIdx.x;
  long xr = (long)n * DIM + e;
  __shared__ float st[DIM], sn[DIM];
  st[e] = ldE(xt, xr, inBf);
  sn[e] = ldE(xn, xr, inBf);
  __syncthreads();
  float acc = 0.f;
  #pragma unroll 8
  for (int k = 0; k < DIM; ++k)
    acc += st[k] * AB[k * DIM + e] + sn[k] * AB[16384 + k * DIM + e];
  H1[(long)n * DIM + e] = acc;
}

// Hraw[n,e] = sum_j relu(H1[n,j]+fb1[j]) * fW2[j,e] + fb2[e]     grid 2048
__global__ __launch_bounds__(128) void gk_h2(const float* __restrict__ H1, const void* __restrict__ fb1,
                                             const void* __restrict__ fW2, const void* __restrict__ fb2,
                                             float* __restrict__ Hraw, const int* __restrict__ dflag) {
  int inBf = *dflag;
  int n = blockIdx.x, e = threadIdx.x;
  __shared__ float a[DIM];
  a[e] = fmaxf(H1[(long)n * DIM + e] + ldE(fb1, e, inBf), 0.f);
  __syncthreads();
  float acc = ldE(fb2, e, inBf);
  #pragma unroll 8
  for (int j = 0; j < DIM; ++j) acc += a[j] * ldE(fW2, (long)j * DIM + e, inBf);
  Hraw[(long)n * DIM + e] = acc;
}

// ---------------------------------------------------------------- reductions
__device__ __forceinline__ float blockSum256(float v, float* s4) {
  #pragma unroll
  for (int o = 32; o > 0; o >>= 1) v += __shfl_down(v, o);
  int t = threadIdx.x;
  if ((t & 63) == 0) s4[t >> 6] = v;
  __syncthreads();
  float r = s4[0] + s4[1] + s4[2] + s4[3];
  __syncthreads();
  return r;
}

__global__ __launch_bounds__(256) void colstats_k(const float* __restrict__ H, float* __restrict__ stats) {
  int e = blockIdx.x;
  __shared__ float sa[4], sb[4], sc[4];
  float sum = 0.f, sq = 0.f, mx = -3.4e38f;
  for (int n = threadIdx.x; n < NTOT; n += 256) {
    float v = H[(long)n * DIM + e];
    sum += v; sq += v * v; mx = fmaxf(mx, v);
  }
  #pragma unroll
  for (int o = 32; o > 0; o >>= 1) {
    sum += __shfl_down(sum, o);
    sq  += __shfl_down(sq, o);
    mx   = fmaxf(mx, __shfl_down(mx, o));
  }
  int t = threadIdx.x;
  if ((t & 63) == 0) { int w = t >> 6; sa[w] = sum; sb[w] = sq; sc[w] = mx; }
  __syncthreads();
  if (t == 0) {
    sum = sa[0]+sa[1]+sa[2]+sa[3];
    sq  = sb[0]+sb[1]+sb[2]+sb[3];
    mx  = fmaxf(fmaxf(sc[0],sc[1]), fmaxf(sc[2],sc[3]));
    float mean = sum * (1.f / NTOT);
    float var  = (sq - sum * mean) * (1.f / (NTOT - 1));
    float ia   = 1.f / (sqrtf(fmaxf(var, 0.f)) + 1e-6f);
    stats[e]         = mean;
    stats[DIM + e]   = ia;
    stats[2*DIM + e] = (mx - mean) * ia;
  }
}

__global__ __launch_bounds__(256) void softmax_k(const float* __restrict__ Hraw, const float* __restrict__ stats,
                                                 float* __restrict__ Hp, float* __restrict__ HTp,
                                                 float* __restrict__ Ecol) {
  int e = blockIdx.x;
  __shared__ float s4[4];
  float mean = stats[e], ia = stats[DIM+e], smax = stats[2*DIM+e];
  float den = 0.f;
  for (int n = threadIdx.x; n < NTOT; n += 256) {
    float s = (Hraw[(long)n*DIM + e] - mean) * ia - smax;
    den += __expf(s);
  }
  den = blockSum256(den, s4);
  float logden = __logf(den);
  float invden = 1.f / den;
  float ent = 0.f;
  for (int n = threadIdx.x; n < NTOT; n += 256) {
    float s = (Hraw[(long)n*DIM + e] - mean) * ia - smax;
    float pv = __expf(s) * invden;
    Hp[(long)n*DIM + e]   = pv;
    HTp[(long)e*NTOT + n] = pv;
    ent += pv * (s - logden);
  }
  ent = blockSum256(ent, s4);
  if (threadIdx.x == 0) Ecol[e] = ent;
}

// tiled pairwise-JSD log part: g[i] -= sum_{j!=i} sum_n (a+b)*log((a+b)/2)
// E-part (126*E_i + S) added in wvec_k.  grid (36 tiles, JNSPLIT), block 256
__global__ __launch_bounds__(256) void jsd_tile(const float* __restrict__ HTp,
                                                float* __restrict__ g) {
  int b = blockIdx.x;
  int bi = 0, rem = b;
  while (rem >= 8 - bi) { rem -= 8 - bi; ++bi; }
  int bj = bi + rem;                      // bi <= bj
  int n0 = blockIdx.y * (NTOT / JNSPLIT);

  __shared__ float Ti[JT][JNC + 2];
  __shared__ float Tj[JT][JNC + 2];
  __shared__ float red[JT][JT + 1];

  int tid = threadIdx.x;
  int ti = tid >> 4, tj = tid & 15;
  bool active = (bi != bj) || (ti < tj);
  float acc = 0.f;

  int lc = tid >> 4;           // load col 0..15
  int ln = (tid & 15) * 8;     // load n base

  for (int c = 0; c < NTOT / JNSPLIT; c += JNC) {
    const float* si = HTp + (long)(bi * JT + lc) * NTOT + n0 + c + ln;
    const float* sj = HTp + (long)(bj * JT + lc) * NTOT + n0 + c + ln;
    #pragma unroll
    for (int r = 0; r < 8; ++r) Ti[lc][ln + r] = si[r];
    #pragma unroll
    for (int r = 0; r < 8; ++r) Tj[lc][ln + r] = sj[r];
    __syncthreads();
    if (active) {
      #pragma unroll 4
      for (int n = 0; n < JNC; ++n) {
        float s = Ti[ti][n] + Tj[tj][n];
        acc += s * __logf(fmaxf(0.5f * s, 1e-38f));
      }
    }
    __syncthreads();
  }

  red[ti][tj] = active ? acc : 0.f;
  __syncthreads();
  if (tid < JT) {
    float s = 0.f;
    #pragma unroll
    for (int j = 0; j < JT; ++j) s += red[tid][j];
    atomicAdd(&g[bi * JT + tid], -s);
  } else if (tid < 2 * JT) {
    int c2 = tid - JT;
    float s = 0.f;
    #pragma unroll
    for (int i = 0; i < JT; ++i) s += red[i][c2];
    atomicAdd(&g[bj * JT + c2], -s);
  }
}

// jm = (g + 126*E + S)/256 -> standardize (ddof=1) -> softmax -> w
__global__ __launch_bounds__(128) void wvec_k(const float* __restrict__ g, const float* __restrict__ Ecol,
                                              float* __restrict__ w) {
  __shared__ float s2[2];
  int t = threadIdx.x;
  float e = Ecol[t];
  float v = e;
  #pragma unroll
  for (int o = 32; o > 0; o >>= 1) v += __shfl_down(v, o);
  if ((t & 63) == 0) s2[t >> 6] = v;
  __syncthreads();
  float S = s2[0] + s2[1];
  __syncthreads();
  float jm = (g[t] + 126.f * e + S) * (1.0f / 256.0f);
  v = jm;
  #pragma unroll
  for (int o = 32; o > 0; o >>= 1) v += __shfl_down(v, o);
  if ((t & 63) == 0) s2[t >> 6] = v;
  __syncthreads();
  float mean = (s2[0] + s2[1]) * (1.0f / 128.0f);
  __syncthreads();
  float d = jm - mean;
  v = d * d;
  #pragma unroll
  for (int o = 32; o > 0; o >>= 1) v += __shfl_down(v, o);
  if ((t & 63) == 0) s2[t >> 6] = v;
  __syncthreads();
  float var = (s2[0] + s2[1]) * (1.0f / 127.0f);
  float njm = d / (sqrtf(var) + 1e-6f);
  __syncthreads();
  v = njm;
  #pragma unroll
  for (int o = 32; o > 0; o >>= 1) v = fmaxf(v, __shfl_down(v, o));
  if ((t & 63) == 0) s2[t >> 6] = v;
  __syncthreads();
  float mx = fmaxf(s2[0], s2[1]);
  float ex = __expf(njm - mx);
  __syncthreads();
  v = ex;
  #pragma unroll
  for (int o = 32; o > 0; o >>= 1) v += __shfl_down(v, o);
  if ((t & 63) == 0) s2[t >> 6] = v;
  __syncthreads();
  w[t] = ex / (s2[0] + s2[1]);
}

// ---------------------------------------------------------------- final chain
// Xz[e][d] = sum_n Hsoft[n,e] x[n][d]   (tiled split-K, atomic into zeroed Xz)
// grid (16, ZSPLIT, 2 batch), block 256
__global__ __launch_bounds__(256) void xz_k(const float* __restrict__ HTp, const void* __restrict__ xt,
                                            const void* __restrict__ xn, float* __restrict__ Xz,
                                            const int* __restrict__ dflag) {
  int inBf = *dflag;
  int bt = blockIdx.z;
  const void* x = bt ? xn : xt;
  float* C = Xz + bt * 16384;
  int e0 = (blockIdx.x & 3) * 32, d0 = (blockIdx.x >> 2) * 32;
  int n0 = blockIdx.y * (NTOT / ZSPLIT);
  __shared__ float As[32][33], Bs[32][33];   // As[n][e], Bs[n][d]
  int tid = threadIdx.x, col = tid & 31, row = tid >> 5;
  int tx = tid & 15, ty = tid >> 4;
  float a00 = 0.f, a01 = 0.f, a10 = 0.f, a11 = 0.f;
  for (int nb = 0; nb < NTOT / ZSPLIT; nb += 32) {
    #pragma unroll
    for (int r = 0; r < 4; ++r) {
      int er = row + r * 8;
      As[col][er] = HTp[(long)(e0 + er) * NTOT + n0 + nb + col];
      Bs[er][col] = ldE(x, (long)(n0 + nb + er) * DIM + d0 + col, inBf);
    }
    __syncthreads();
    #pragma unroll
    for (int nn = 0; nn < 32; ++nn) {
      float e0v = As[nn][2*ty], e1v = As[nn][2*ty+1];
      float d0v = Bs[nn][2*tx], d1v = Bs[nn][2*tx+1];
      a00 += e0v * d0v; a01 += e0v * d1v;
      a10 += e1v * d0v; a11 += e1v * d1v;
    }
    __syncthreads();
  }
  int e = e0 + 2 * ty, d = d0 + 2 * tx;
  atomicAdd(&C[e * DIM + d],           a00);
  atomicAdd(&C[e * DIM + d + 1],       a01);
  atomicAdd(&C[(e + 1) * DIM + d],     a10);
  atomicAdd(&C[(e + 1) * DIM + d + 1], a11);
}

// Zw[e][d] = w[e] * sum_k Xz[e][k] * theta[k][d]    grid (128, 2 batch)
__global__ __launch_bounds__(128) void zs_k(const float* __restrict__ Xz, const void* __restrict__ thT,
                                            const void* __restrict__ thN, const float* __restrict__ w,
                                            float* __restrict__ Zw, const int* __restrict__ dflag) {
  int inBf = *dflag;
  int e = blockIdx.x, d = threadIdx.x, bt = blockIdx.y;
  const float* src = Xz + bt * 16384 + e * DIM;
  const void* th = bt ? thN : thT;
  __shared__ float s[DIM];
  s[d] = src[d];
  __syncthreads();
  float acc = 0.f;
  #pragma unroll 8
  for (int k = 0; k < DIM; ++k) acc += s[k] * ldE(th, (long)k * DIM + d, inBf);
  Zw[bt * 16384 + e * DIM + d] = acc * w[e];
}

// out[n][d] = x[n][d] + elu( sum_e Hsoft[n,e] Zw[e][d] )  (tiled, fused epilogue)
// grid (4, 64, 2 batch), block 256
__global__ __launch_bounds__(256) void uk_t(const float* __restrict__ Hp, const float* __restrict__ Zw,
                                            const void* __restrict__ xt, const void* __restrict__ xn,
                                            float* __restrict__ out, const int* __restrict__ dflag) {
  int inBf = *dflag;
  int bt = blockIdx.z;
  const void* x = bt ? xn : xt;
  const float* B = Zw + bt * 16384;
  float* o = out + (long)bt * NTOT * DIM;
  int d0 = blockIdx.x * 32, n0 = blockIdx.y * 32;
  __shared__ float As[32][33], Bs[32][33];   // As[n][e], Bs[e][d]
  int tid = threadIdx.x, col = tid & 31, row = tid >> 5;
  int tx = tid & 15, ty = tid >> 4;
  float a00 = 0.f, a01 = 0.f, a10 = 0.f, a11 = 0.f;
  for (int eb = 0; eb < DIM; eb += 32) {
    #pragma unroll
    for (int r = 0; r < 4; ++r) {
      int rr = row + r * 8;
      As[rr][col] = Hp[(long)(n0 + rr) * DIM + eb + col];
      Bs[rr][col] = B[(long)(eb + rr) * DIM + d0 + col];
    }
    __syncthreads();
    #pragma unroll
    for (int ee = 0; ee < 32; ++ee) {
      float x0 = As[2*ty][ee], x1 = As[2*ty+1][ee];
      float b0 = Bs[ee][2*tx], b1 = Bs[ee][2*tx+1];
      a00 += x0 * b0; a01 += x0 * b1;
      a10 += x1 * b0; a11 += x1 * b1;
    }
    __syncthreads();
  }
  int n = n0 + 2 * ty, d = d0 + 2 * tx;
  long i0 = (long)n * DIM + d, i1 = i0 + DIM;
  float e00 = a00 > 0.f ? a00 : expm1f(a00);
  float e01 = a01 > 0.f ? a01 : expm1f(a01);
  float e10 = a10 > 0.f ? a10 : expm1f(a10);
  float e11 = a11 > 0.f ? a11 : expm1f(a11);
  o[i0]     = ldE(x, i0, inBf)     + e00;
  o[i0 + 1] = ldE(x, i0 + 1, inBf) + e01;
  o[i1]     = ldE(x, i1, inBf)     + e10;
  o[i1 + 1] = ldE(x, i1 + 1, inBf) + e11;
}

// ---------------------------------------------------------------- launcher
extern "C" void kernel_launch(void* const* d_in, const int* in_sizes, int n_in,
                              void* d_out, int out_size, void* d_ws, size_t ws_size,
                              hipStream_t stream) {
  const void* xt = d_in[0];   // x_time
  const void* xn = d_in[1];   // x_news
  const void *W1[4], *b1[4], *W2[4], *b2[4];
  for (int k = 0; k < 4; ++k) {           // it, inw, t2n, n2t
    W1[k] = d_in[2 + 4*k];
    b1[k] = d_in[3 + 4*k];
    W2[k] = d_in[4 + 4*k];
    b2[k] = d_in[5 + 4*k];
  }
  const void* fW1 = d_in[18];
  const void* fb1 = d_in[19];
  const void* fW2 = d_in[20];
  const void* fb2 = d_in[21];
  const void* thT = d_in[22];
  const void* thN = d_in[23];

  // ws map (floats), peak 1016832 = 4.07 MB
  float* ws    = (float*)d_ws;
  int*   Flag  = (int*)ws;            // [0,128)
  float* Gacc  = ws + 128;            // [128,256)    zeroed (jsd atomics)
  float* stats = ws + 256;            // [256,768)    mean|ia|smax|Ecol
  float* Ecol  = stats + 3*DIM;
  float* Wv    = ws + 768;            // [768,896)
  float* Xz    = ws + 1024;           // [1024,33792)   zeroed (xz_k atomics, 2 batch)
  float* Zw    = ws + 33792;          // [33792,66560)  (2 batch)
  float* G     = ws + 66560;          // [66560,132096) zeroed (gk_mlp1t atomics)
  float* Mk    = ws + 132096;         // [132096,197632)
  float* AB    = ws + 197632;         // [197632,230400)
  float* H1    = ws + 230400;         // [230400,492544) -> Hp after softmax
  float* Hp    = H1;
  float* Hraw  = ws + 492544;         // [492544,754688)
  float* HTp   = ws + 754688;         // [754688,1016832)

  float* out = (float*)d_out;         // f32 output, [time | news]

  detect_k<<<1, 64, 0, stream>>>(xt, Flag);
  // zero [128,132096): Gacc, stats/Wv (overwritten anyway), Xz, Zw, G
  zero_k<<<(131968 + 255) / 256, 256, 0, stream>>>(ws + 128, 131968);

  P4 Xs  = {{xt, xn, xn, xt}};
  P4 W1s = {{W1[0], W1[1], W1[2], W1[3]}};
  P4 B1s = {{b1[0], b1[1], b1[2], b1[3]}};
  P4 W2s = {{W2[0], W2[1], W2[2], W2[3]}};
  P4 B2s = {{b2[0], b2[1], b2[2], b2[3]}};

  gk_mlp1t<<<dim3(16, MSPLIT, 4), 256, 0, stream>>>(Xs, W1s, G, Flag);
  gk_mlp2<<<dim3(128, 4), 128, 0, stream>>>(G, B1s, W2s, B2s, Mk, Flag);
  gk_ab  <<<dim3(128, 2), 128, 0, stream>>>(Mk, fW1, AB, Flag);
  gk_h1  <<<NTOT, 128, 0, stream>>>(xt, xn, AB, H1, Flag);
  gk_h2  <<<NTOT, 128, 0, stream>>>(H1, fb1, fW2, fb2, Hraw, Flag);

  colstats_k<<<DIM, 256, 0, stream>>>(Hraw, stats);
  softmax_k<<<DIM, 256, 0, stream>>>(Hraw, stats, Hp, HTp, Ecol);

  jsd_tile<<<dim3(36, JNSPLIT), 256, 0, stream>>>(HTp, Gacc);
  wvec_k<<<1, 128, 0, stream>>>(Gacc, Ecol, Wv);

  // z = (H^T x) theta  (reassociated), scaled by w; then out = x + elu(H @ Zw)
  xz_k<<<dim3(16, ZSPLIT, 2), 256, 0, stream>>>(HTp, xt, xn, Xz, Flag);
  zs_k<<<dim3(128, 2), 128, 0, stream>>>(Xz, thT, thN, Wv, Zw, Flag);
  uk_t<<<dim3(4, 64, 2), 256, 0, stream>>>(Hp, Zw, xt, xn, out, Flag);

  (void)in_sizes; (void)n_in; (void)out_size; (void)ws_size;
}

// Round 15
// 235.921 us; speedup vs baseline: 4.2296x; 1.0500x over previous
//
#include <hip/hip_runtime.h>
#include <hip/hip_bf16.h>
#include <math.h>

typedef __hip_bfloat16 bf16;

#define NTOT 2048   // N*T
#define DIM  128    // D == E1
#define MSPLIT 8    // split-K for gk_mlp1t
#define ZSPLIT 8    // split-K for xz_k
#define JT 16       // jsd tile width (columns)
#define JNC 128     // jsd n-chunk in LDS
#define JNSPLIT 8   // jsd n splits

__device__ __forceinline__ float ldE(const void* p, long idx, int isBf16) {
  return isBf16 ? __bfloat162float(((const bf16*)p)[idx]) : ((const float*)p)[idx];
}

struct P4 { const void* p[4]; };

// fused: block 0 detects input dtype; all other blocks zero the accumulators
__global__ void zd_k(const void* x, int* flag, float* zp, int zn) {
  if (blockIdx.x == 0) {
    if (threadIdx.x < 64) {
      const bf16* hb = (const bf16*)x;
      float mx = 0.f;
      for (int i = threadIdx.x; i < 256; i += 64) {
        float v = fabsf(__bfloat162float(hb[i]));
        if (!isfinite(v)) v = 1e30f;
        mx = fmaxf(mx, v);
      }
      #pragma unroll
      for (int o = 32; o > 0; o >>= 1) mx = fmaxf(mx, __shfl_down(mx, o));
      if (threadIdx.x == 0) *flag = (mx < 100.f) ? 1 : 0;
    }
  } else {
    int i = (blockIdx.x - 1) * 256 + threadIdx.x;
    if (i < zn) zp[i] = 0.f;
  }
}

// ---------------------------------------------------------------- H pipeline
// G_k = X_k^T @ W1_k  (tiled split-K, atomic accumulate into zeroed G)
__global__ __launch_bounds__(256) void gk_mlp1t(P4 X, P4 W1, float* __restrict__ G,
                                                const int* __restrict__ dflag) {
  int inBf = *dflag;
  int k = blockIdx.z;
  int m0 = (blockIdx.x & 3) * 32;
  int e0 = (blockIdx.x >> 2) * 32;
  int n0 = blockIdx.y * (NTOT / MSPLIT);
  const void* Xp = X.p[k];
  const void* Wp = W1.p[k];
  __shared__ float Xs[32][33], Ws[32][33];
  int tid = threadIdx.x;
  int col = tid & 31;
  int row = tid >> 5;
  int tx = tid & 15, ty = tid >> 4;
  float a00 = 0.f, a01 = 0.f, a10 = 0.f, a11 = 0.f;
  for (int nb = 0; nb < NTOT / MSPLIT; nb += 32) {
    #pragma unroll
    for (int r = 0; r < 4; ++r) {
      int nn = row + r * 8;
      long gn = (long)(n0 + nb + nn) * DIM;
      Xs[nn][col] = ldE(Xp, gn + m0 + col, inBf);
      Ws[nn][col] = ldE(Wp, gn + e0 + col, inBf);
    }
    __syncthreads();
    #pragma unroll
    for (int nn = 0; nn < 32; ++nn) {
      float x0 = Xs[nn][2*ty], x1 = Xs[nn][2*ty+1];
      float w0 = Ws[nn][2*tx], w1 = Ws[nn][2*tx+1];
      a00 += x0 * w0; a01 += x0 * w1;
      a10 += x1 * w0; a11 += x1 * w1;
    }
    __syncthreads();
  }
  float* Gk = G + (long)k * 16384;
  int m = m0 + 2 * ty, e = e0 + 2 * tx;
  atomicAdd(&Gk[m * DIM + e],           a00);
  atomicAdd(&Gk[m * DIM + e + 1],       a01);
  atomicAdd(&Gk[(m + 1) * DIM + e],     a10);
  atomicAdd(&Gk[(m + 1) * DIM + e + 1], a11);
}

// M_k[m,e] = sum_j relu(G_k[m,j]+b1_k[j]) * W2_k[j,e] + b2_k[e]   grid (128,4)
__global__ __launch_bounds__(128) void gk_mlp2(const float* __restrict__ G, P4 B1, P4 W2, P4 B2,
                                               float* __restrict__ M, const int* __restrict__ dflag) {
  int inBf = *dflag;
  int m = blockIdx.x, e = threadIdx.x, k = blockIdx.y;
  __shared__ float a[DIM];
  a[e] = fmaxf(G[(long)k * 16384 + m * DIM + e] + ldE(B1.p[k], e, inBf), 0.f);
  __syncthreads();
  const void* Wp = W2.p[k];
  float acc = ldE(B2.p[k], e, inBf);
  #pragma unroll 8
  for (int j = 0; j < DIM; ++j) acc += a[j] * ldE(Wp, (long)j * DIM + e, inBf);
  M[(long)k * 16384 + m * DIM + e] = acc;
}

// h=0: A_t[k,e] = sum_j M_it[k,j]*fW1[j,e]      + M_t2n[k,j]*fW1[256+j,e]
// h=1: B_n[k,e] = sum_j M_inw[k,j]*fW1[128+j,e] + M_n2t[k,j]*fW1[384+j,e]
__global__ __launch_bounds__(128) void gk_ab(const float* __restrict__ Mk, const void* __restrict__ fW1,
                                             float* __restrict__ AB, const int* __restrict__ dflag) {
  int inBf = *dflag;
  int k = blockIdx.x, e = threadIdx.x, h = blockIdx.y;
  const float* Ma = Mk + (h == 0 ? 0 : 1) * 16384;
  const float* Mb = Mk + (h == 0 ? 2 : 3) * 16384;
  int r0 = (h == 0) ? 0 : 128, r1 = (h == 0) ? 256 : 384;
  __shared__ float sa[DIM], sb[DIM];
  sa[e] = Ma[k * DIM + e];
  sb[e] = Mb[k * DIM + e];
  __syncthreads();
  float acc = 0.f;
  #pragma unroll 8
  for (int j = 0; j < DIM; ++j)
    acc += sa[j] * ldE(fW1, (long)(r0 + j) * DIM + e, inBf)
         + sb[j] * ldE(fW1, (long)(r1 + j) * DIM + e, inBf);
  AB[(long)h * 16384 + k * DIM + e] = acc;
}

// fused H1+H2: per row n — H1 row kept in LDS
// Hraw[n,e] = sum_j relu( (sum_k xt[n,k]A[k,j]+xn[n,k]B[k,j]) + fb1[j] ) fW2[j,e] + fb2[e]
__global__ __launch_bounds__(128) void gk_h12(const void* __restrict__ xt, const void* __restrict__ xn,
                                              const float* __restrict__ AB, const void* __restrict__ fb1,
                                              const void* __restrict__ fW2, const void* __restrict__ fb2,
                                              float* __restrict__ Hraw, const int* __restrict__ dflag) {
  int inBf = *dflag;
  int n = blockIdx.x, e = threadIdx.x;
  long xr = (long)n * DIM + e;
  __shared__ float st[DIM], sn[DIM], h1[DIM];
  st[e] = ldE(xt, xr, inBf);
  sn[e] = ldE(xn, xr, inBf);
  __syncthreads();
  float acc = 0.f;
  #pragma unroll 8
  for (int k = 0; k < DIM; ++k)
    acc += st[k] * AB[k * DIM + e] + sn[k] * AB[16384 + k * DIM + e];
  h1[e] = fmaxf(acc + ldE(fb1, e, inBf), 0.f);
  __syncthreads();
  float acc2 = ldE(fb2, e, inBf);
  #pragma unroll 8
  for (int j = 0; j < DIM; ++j) acc2 += h1[j] * ldE(fW2, (long)j * DIM + e, inBf);
  Hraw[(long)n * DIM + e] = acc2;
}

// ---------------------------------------------------------------- reductions
// fused colstats+softmax: one block per column e, column register-resident.
// Single uncoalesced read pass; writes HTp (coalesced) + Ecol. No Hp.
__global__ __launch_bounds__(256) void colsoft_k(const float* __restrict__ Hraw,
                                                 float* __restrict__ HTp, float* __restrict__ Ecol) {
  int e = blockIdx.x;
  int t = threadIdx.x;
  __shared__ float sa[4], sb[4], sc[4];
  float v[8];
  float sum = 0.f, sq = 0.f, mx = -3.4e38f;
  #pragma unroll
  for (int r = 0; r < 8; ++r) {
    float x = Hraw[(long)(t + 256 * r) * DIM + e];
    v[r] = x;
    sum += x; sq += x * x; mx = fmaxf(mx, x);
  }
  #pragma unroll
  for (int o = 32; o > 0; o >>= 1) {
    sum += __shfl_down(sum, o);
    sq  += __shfl_down(sq, o);
    mx   = fmaxf(mx, __shfl_down(mx, o));
  }
  if ((t & 63) == 0) { int w = t >> 6; sa[w] = sum; sb[w] = sq; sc[w] = mx; }
  __syncthreads();
  sum = sa[0] + sa[1] + sa[2] + sa[3];
  sq  = sb[0] + sb[1] + sb[2] + sb[3];
  mx  = fmaxf(fmaxf(sc[0], sc[1]), fmaxf(sc[2], sc[3]));
  float mean = sum * (1.f / NTOT);
  float var  = (sq - sum * mean) * (1.f / (NTOT - 1));
  float ia   = 1.f / (sqrtf(fmaxf(var, 0.f)) + 1e-6f);
  float smax = (mx - mean) * ia;
  __syncthreads();

  float den = 0.f;
  #pragma unroll
  for (int r = 0; r < 8; ++r) {
    float s = (v[r] - mean) * ia - smax;
    v[r] = s;
    den += __expf(s);
  }
  #pragma unroll
  for (int o = 32; o > 0; o >>= 1) den += __shfl_down(den, o);
  if ((t & 63) == 0) sa[t >> 6] = den;
  __syncthreads();
  den = sa[0] + sa[1] + sa[2] + sa[3];
  float logden = __logf(den);
  float invden = 1.f / den;
  __syncthreads();

  float ent = 0.f;
  #pragma unroll
  for (int r = 0; r < 8; ++r) {
    float s = v[r];
    float pv = __expf(s) * invden;
    HTp[(long)e * NTOT + t + 256 * r] = pv;
    ent += pv * (s - logden);
  }
  #pragma unroll
  for (int o = 32; o > 0; o >>= 1) ent += __shfl_down(ent, o);
  if ((t & 63) == 0) sa[t >> 6] = ent;
  __syncthreads();
  if (t == 0) Ecol[e] = sa[0] + sa[1] + sa[2] + sa[3];
}

// tiled pairwise-JSD log part: g[i] -= sum_{j!=i} sum_n (a+b)*log((a+b)/2)
__global__ __launch_bounds__(256) void jsd_tile(const float* __restrict__ HTp,
                                                float* __restrict__ g) {
  int b = blockIdx.x;
  int bi = 0, rem = b;
  while (rem >= 8 - bi) { rem -= 8 - bi; ++bi; }
  int bj = bi + rem;                      // bi <= bj
  int n0 = blockIdx.y * (NTOT / JNSPLIT);

  __shared__ float Ti[JT][JNC + 2];
  __shared__ float Tj[JT][JNC + 2];
  __shared__ float red[JT][JT + 1];

  int tid = threadIdx.x;
  int ti = tid >> 4, tj = tid & 15;
  bool active = (bi != bj) || (ti < tj);
  float acc = 0.f;

  int lc = tid >> 4;
  int ln = (tid & 15) * 8;

  for (int c = 0; c < NTOT / JNSPLIT; c += JNC) {
    const float* si = HTp + (long)(bi * JT + lc) * NTOT + n0 + c + ln;
    const float* sj = HTp + (long)(bj * JT + lc) * NTOT + n0 + c + ln;
    #pragma unroll
    for (int r = 0; r < 8; ++r) Ti[lc][ln + r] = si[r];
    #pragma unroll
    for (int r = 0; r < 8; ++r) Tj[lc][ln + r] = sj[r];
    __syncthreads();
    if (active) {
      #pragma unroll 4
      for (int n = 0; n < JNC; ++n) {
        float s = Ti[ti][n] + Tj[tj][n];
        acc += s * __logf(fmaxf(0.5f * s, 1e-38f));
      }
    }
    __syncthreads();
  }

  red[ti][tj] = active ? acc : 0.f;
  __syncthreads();
  if (tid < JT) {
    float s = 0.f;
    #pragma unroll
    for (int j = 0; j < JT; ++j) s += red[tid][j];
    atomicAdd(&g[bi * JT + tid], -s);
  } else if (tid < 2 * JT) {
    int c2 = tid - JT;
    float s = 0.f;
    #pragma unroll
    for (int i = 0; i < JT; ++i) s += red[i][c2];
    atomicAdd(&g[bj * JT + c2], -s);
  }
}

// jm = (g + 126*E + S)/256 -> standardize (ddof=1) -> softmax -> w
__global__ __launch_bounds__(128) void wvec_k(const float* __restrict__ g, const float* __restrict__ Ecol,
                                              float* __restrict__ w) {
  __shared__ float s2[2];
  int t = threadIdx.x;
  float e = Ecol[t];
  float v = e;
  #pragma unroll
  for (int o = 32; o > 0; o >>= 1) v += __shfl_down(v, o);
  if ((t & 63) == 0) s2[t >> 6] = v;
  __syncthreads();
  float S = s2[0] + s2[1];
  __syncthreads();
  float jm = (g[t] + 126.f * e + S) * (1.0f / 256.0f);
  v = jm;
  #pragma unroll
  for (int o = 32; o > 0; o >>= 1) v += __shfl_down(v, o);
  if ((t & 63) == 0) s2[t >> 6] = v;
  __syncthreads();
  float mean = (s2[0] + s2[1]) * (1.0f / 128.0f);
  __syncthreads();
  float d = jm - mean;
  v = d * d;
  #pragma unroll
  for (int o = 32; o > 0; o >>= 1) v += __shfl_down(v, o);
  if ((t & 63) == 0) s2[t >> 6] = v;
  __syncthreads();
  float var = (s2[0] + s2[1]) * (1.0f / 127.0f);
  float njm = d / (sqrtf(var) + 1e-6f);
  __syncthreads();
  v = njm;
  #pragma unroll
  for (int o = 32; o > 0; o >>= 1) v = fmaxf(v, __shfl_down(v, o));
  if ((t & 63) == 0) s2[t >> 6] = v;
  __syncthreads();
  float mx = fmaxf(s2[0], s2[1]);
  float ex = __expf(njm - mx);
  __syncthreads();
  v = ex;
  #pragma unroll
  for (int o = 32; o > 0; o >>= 1) v += __shfl_down(v, o);
  if ((t & 63) == 0) s2[t >> 6] = v;
  __syncthreads();
  w[t] = ex / (s2[0] + s2[1]);
}

// ---------------------------------------------------------------- final chain
// Xz[e][d] = sum_n Hsoft[n,e] x[n][d]   (tiled split-K, atomic into zeroed Xz)
__global__ __launch_bounds__(256) void xz_k(const float* __restrict__ HTp, const void* __restrict__ xt,
                                            const void* __restrict__ xn, float* __restrict__ Xz,
                                            const int* __restrict__ dflag) {
  int inBf = *dflag;
  int bt = blockIdx.z;
  const void* x = bt ? xn : xt;
  float* C = Xz + bt * 16384;
  int e0 = (blockIdx.x & 3) * 32, d0 = (blockIdx.x >> 2) * 32;
  int n0 = blockIdx.y * (NTOT / ZSPLIT);
  __shared__ float As[32][33], Bs[32][33];   // As[n][e], Bs[n][d]
  int tid = threadIdx.x, col = tid & 31, row = tid >> 5;
  int tx = tid & 15, ty = tid >> 4;
  float a00 = 0.f, a01 = 0.f, a10 = 0.f, a11 = 0.f;
  for (int nb = 0; nb < NTOT / ZSPLIT; nb += 32) {
    #pragma unroll
    for (int r = 0; r < 4; ++r) {
      int er = row + r * 8;
      As[col][er] = HTp[(long)(e0 + er) * NTOT + n0 + nb + col];
      Bs[er][col] = ldE(x, (long)(n0 + nb + er) * DIM + d0 + col, inBf);
    }
    __syncthreads();
    #pragma unroll
    for (int nn = 0; nn < 32; ++nn) {
      float e0v = As[nn][2*ty], e1v = As[nn][2*ty+1];
      float d0v = Bs[nn][2*tx], d1v = Bs[nn][2*tx+1];
      a00 += e0v * d0v; a01 += e0v * d1v;
      a10 += e1v * d0v; a11 += e1v * d1v;
    }
    __syncthreads();
  }
  int e = e0 + 2 * ty, d = d0 + 2 * tx;
  atomicAdd(&C[e * DIM + d],           a00);
  atomicAdd(&C[e * DIM + d + 1],       a01);
  atomicAdd(&C[(e + 1) * DIM + d],     a10);
  atomicAdd(&C[(e + 1) * DIM + d + 1], a11);
}

// Zw[e][d] = w[e] * sum_k Xz[e][k] * theta[k][d]    grid (128, 2 batch)
__global__ __launch_bounds__(128) void zs_k(const float* __restrict__ Xz, const void* __restrict__ thT,
                                            const void* __restrict__ thN, const float* __restrict__ w,
                                            float* __restrict__ Zw, const int* __restrict__ dflag) {
  int inBf = *dflag;
  int e = blockIdx.x, d = threadIdx.x, bt = blockIdx.y;
  const float* src = Xz + bt * 16384 + e * DIM;
  const void* th = bt ? thN : thT;
  __shared__ float s[DIM];
  s[d] = src[d];
  __syncthreads();
  float acc = 0.f;
  #pragma unroll 8
  for (int k = 0; k < DIM; ++k) acc += s[k] * ldE(th, (long)k * DIM + d, inBf);
  Zw[bt * 16384 + e * DIM + d] = acc * w[e];
}

// out[n][d] = x[n][d] + elu( sum_e Hsoft[n,e] Zw[e][d] )  (reads H from HTp)
// grid (4, 64, 2 batch), block 256
__global__ __launch_bounds__(256) void uk_t(const float* __restrict__ HTp, const float* __restrict__ Zw,
                                            const void* __restrict__ xt, const void* __restrict__ xn,
                                            float* __restrict__ out, const int* __restrict__ dflag) {
  int inBf = *dflag;
  int bt = blockIdx.z;
  const void* x = bt ? xn : xt;
  const float* B = Zw + bt * 16384;
  float* o = out + (long)bt * NTOT * DIM;
  int d0 = blockIdx.x * 32, n0 = blockIdx.y * 32;
  __shared__ float As[32][33], Bs[32][33];   // As[n][e], Bs[e][d]
  int tid = threadIdx.x, col = tid & 31, row = tid >> 5;
  int tx = tid & 15, ty = tid >> 4;
  float a00 = 0.f, a01 = 0.f, a10 = 0.f, a11 = 0.f;
  for (int eb = 0; eb < DIM; eb += 32) {
    #pragma unroll
    for (int r = 0; r < 4; ++r) {
      int rr = row + r * 8;
      As[col][rr] = HTp[(long)(eb + rr) * NTOT + n0 + col];   // coalesced along n
      Bs[rr][col] = B[(long)(eb + rr) * DIM + d0 + col];
    }
    __syncthreads();
    #pragma unroll
    for (int ee = 0; ee < 32; ++ee) {
      float x0 = As[2*ty][ee], x1 = As[2*ty+1][ee];
      float b0 = Bs[ee][2*tx], b1 = Bs[ee][2*tx+1];
      a00 += x0 * b0; a01 += x0 * b1;
      a10 += x1 * b0; a11 += x1 * b1;
    }
    __syncthreads();
  }
  int n = n0 + 2 * ty, d = d0 + 2 * tx;
  long i0 = (long)n * DIM + d, i1 = i0 + DIM;
  float e00 = a00 > 0.f ? a00 : expm1f(a00);
  float e01 = a01 > 0.f ? a01 : expm1f(a01);
  float e10 = a10 > 0.f ? a10 : expm1f(a10);
  float e11 = a11 > 0.f ? a11 : expm1f(a11);
  o[i0]     = ldE(x, i0, inBf)     + e00;
  o[i0 + 1] = ldE(x, i0 + 1, inBf) + e01;
  o[i1]     = ldE(x, i1, inBf)     + e10;
  o[i1 + 1] = ldE(x, i1 + 1, inBf) + e11;
}

// ---------------------------------------------------------------- launcher
extern "C" void kernel_launch(void* const* d_in, const int* in_sizes, int n_in,
                              void* d_out, int out_size, void* d_ws, size_t ws_size,
                              hipStream_t stream) {
  const void* xt = d_in[0];   // x_time
  const void* xn = d_in[1];   // x_news
  const void *W1[4], *b1[4], *W2[4], *b2[4];
  for (int k = 0; k < 4; ++k) {           // it, inw, t2n, n2t
    W1[k] = d_in[2 + 4*k];
    b1[k] = d_in[3 + 4*k];
    W2[k] = d_in[4 + 4*k];
    b2[k] = d_in[5 + 4*k];
  }
  const void* fW1 = d_in[18];
  const void* fb1 = d_in[19];
  const void* fW2 = d_in[20];
  const void* fb2 = d_in[21];
  const void* thT = d_in[22];
  const void* thN = d_in[23];

  // ws map (floats), peak 754176 = 3.02 MB
  float* ws    = (float*)d_ws;
  int*   Flag  = (int*)ws;            // [0,128)
  float* Gacc  = ws + 128;            // [128,256)     zeroed (jsd atomics)
  float* Ecol  = ws + 256;            // [256,384)
  float* Wv    = ws + 384;            // [384,512)
  float* Xz    = ws + 512;            // [512,33280)   zeroed (xz_k atomics, 2 batch)
  float* Zw    = ws + 33280;          // [33280,66048) (2 batch)
  float* G     = ws + 66048;          // [66048,131584) zeroed (gk_mlp1t atomics)
  float* Mk    = ws + 131584;         // [131584,197120)
  float* AB    = ws + 197120;         // [197120,229888)
  float* Hraw  = ws + 229888;         // [229888,492032)
  float* HTp   = ws + 492032;         // [492032,754176)

  float* out = (float*)d_out;         // f32 output, [time | news]

  // fused zero+detect: zero [128,131584) = 131456 floats
  zd_k<<<1 + (131456 + 255) / 256, 256, 0, stream>>>(xt, Flag, ws + 128, 131456);

  P4 Xs  = {{xt, xn, xn, xt}};
  P4 W1s = {{W1[0], W1[1], W1[2], W1[3]}};
  P4 B1s = {{b1[0], b1[1], b1[2], b1[3]}};
  P4 W2s = {{W2[0], W2[1], W2[2], W2[3]}};
  P4 B2s = {{b2[0], b2[1], b2[2], b2[3]}};

  gk_mlp1t<<<dim3(16, MSPLIT, 4), 256, 0, stream>>>(Xs, W1s, G, Flag);
  gk_mlp2<<<dim3(128, 4), 128, 0, stream>>>(G, B1s, W2s, B2s, Mk, Flag);
  gk_ab  <<<dim3(128, 2), 128, 0, stream>>>(Mk, fW1, AB, Flag);
  gk_h12 <<<NTOT, 128, 0, stream>>>(xt, xn, AB, fb1, fW2, fb2, Hraw, Flag);

  colsoft_k<<<DIM, 256, 0, stream>>>(Hraw, HTp, Ecol);

  jsd_tile<<<dim3(36, JNSPLIT), 256, 0, stream>>>(HTp, Gacc);
  wvec_k<<<1, 128, 0, stream>>>(Gacc, Ecol, Wv);

  // z = (H^T x) theta (reassociated), scaled by w; then out = x + elu(H @ Zw)
  xz_k<<<dim3(16, ZSPLIT, 2), 256, 0, stream>>>(HTp, xt, xn, Xz, Flag);
  zs_k<<<dim3(128, 2), 128, 0, stream>>>(Xz, thT, thN, Wv, Zw, Flag);
  uk_t<<<dim3(4, 64, 2), 256, 0, stream>>>(HTp, Zw, xt, xn, out, Flag);

  (void)in_sizes; (void)n_in; (void)out_size; (void)ws_size;
}

// Round 16
// 190.351 us; speedup vs baseline: 5.2422x; 1.2394x over previous
//
#include <hip/hip_runtime.h>
#include <hip/hip_bf16.h>
#include <math.h>

#define NTOT 2048   // N*T
#define DIM  128    // D == E1
#define MSPLIT 8    // split-K for gk_mlp1t
#define ZSPLIT 8    // split-K for xz_k
#define JT 16       // jsd tile width (columns)
#define JNC 128     // jsd n-chunk in LDS
#define JNSPLIT 8   // jsd n splits

struct P4 { const float* p[4]; };

// ---------------------------------------------------------------- H pipeline
// Gs[k][split] = partial X_k^T @ W1_k  (no atomics; consumer sums splits)
// grid (16 tiles, MSPLIT, 4 k), block 256
__global__ __launch_bounds__(256) void gk_mlp1t(P4 X, P4 W1, float* __restrict__ Gs) {
  int k = blockIdx.z;
  int m0 = (blockIdx.x & 3) * 32;
  int e0 = (blockIdx.x >> 2) * 32;
  int split = blockIdx.y;
  int n0 = split * (NTOT / MSPLIT);
  const float* Xp = X.p[k];
  const float* Wp = W1.p[k];
  __shared__ float Xs[32][36], Ws[32][36];   // 36: row-aligned for b128 stores
  int tid = threadIdx.x;
  int lr = tid >> 3;              // load row 0..31
  int lc = (tid & 7) * 4;         // load col 0,4,..28
  int tx = tid & 15, ty = tid >> 4;
  float a00 = 0.f, a01 = 0.f, a10 = 0.f, a11 = 0.f;
  for (int nb = 0; nb < NTOT / MSPLIT; nb += 32) {
    long gn = (long)(n0 + nb + lr) * DIM;
    float4 xv = *(const float4*)(Xp + gn + m0 + lc);
    float4 wv = *(const float4*)(Wp + gn + e0 + lc);
    *(float4*)&Xs[lr][lc] = xv;
    *(float4*)&Ws[lr][lc] = wv;
    __syncthreads();
    #pragma unroll
    for (int nn = 0; nn < 32; ++nn) {
      float x0 = Xs[nn][2*ty], x1 = Xs[nn][2*ty+1];
      float w0 = Ws[nn][2*tx], w1 = Ws[nn][2*tx+1];
      a00 += x0 * w0; a01 += x0 * w1;
      a10 += x1 * w0; a11 += x1 * w1;
    }
    __syncthreads();
  }
  float* Gk = Gs + ((long)k * MSPLIT + split) * 16384;
  int m = m0 + 2 * ty, e = e0 + 2 * tx;
  Gk[m * DIM + e]           = a00;
  Gk[m * DIM + e + 1]       = a01;
  Gk[(m + 1) * DIM + e]     = a10;
  Gk[(m + 1) * DIM + e + 1] = a11;
}

// M_k[m,e] = sum_j relu(sum_s Gs[k][s][m,j] + b1_k[j]) * W2_k[j,e] + b2_k[e]
// grid (128, 4), block 128
__global__ __launch_bounds__(128) void gk_mlp2(const float* __restrict__ Gs, P4 B1, P4 W2, P4 B2,
                                               float* __restrict__ M) {
  int m = blockIdx.x, e = threadIdx.x, k = blockIdx.y;
  __shared__ float a[DIM];
  const float* Gk = Gs + (long)k * MSPLIT * 16384 + m * DIM + e;
  float g = 0.f;
  #pragma unroll
  for (int s = 0; s < MSPLIT; ++s) g += Gk[s * 16384];
  a[e] = fmaxf(g + B1.p[k][e], 0.f);
  __syncthreads();
  const float* Wp = W2.p[k];
  float acc = B2.p[k][e];
  #pragma unroll 8
  for (int j = 0; j < DIM; ++j) acc += a[j] * Wp[(long)j * DIM + e];
  M[(long)k * 16384 + m * DIM + e] = acc;
}

// h=0: A_t[k,e] = sum_j M_it[k,j]*fW1[j,e]      + M_t2n[k,j]*fW1[256+j,e]
// h=1: B_n[k,e] = sum_j M_inw[k,j]*fW1[128+j,e] + M_n2t[k,j]*fW1[384+j,e]
__global__ __launch_bounds__(128) void gk_ab(const float* __restrict__ Mk, const float* __restrict__ fW1,
                                             float* __restrict__ AB) {
  int k = blockIdx.x, e = threadIdx.x, h = blockIdx.y;
  const float* Ma = Mk + (h == 0 ? 0 : 1) * 16384;
  const float* Mb = Mk + (h == 0 ? 2 : 3) * 16384;
  const float* W0 = fW1 + (h == 0 ? 0 : 128) * DIM;
  const float* W1p = fW1 + (h == 0 ? 256 : 384) * DIM;
  __shared__ float sa[DIM], sb[DIM];
  sa[e] = Ma[k * DIM + e];
  sb[e] = Mb[k * DIM + e];
  __syncthreads();
  float acc = 0.f;
  #pragma unroll 8
  for (int j = 0; j < DIM; ++j)
    acc += sa[j] * W0[(long)j * DIM + e] + sb[j] * W1p[(long)j * DIM + e];
  AB[(long)h * 16384 + k * DIM + e] = acc;
}

// fused H1+H2 per row n (H1 row in LDS):
// Hraw[n,e] = sum_j relu( (sum_k xt[n,k]A[k,j]+xn[n,k]B[k,j]) + fb1[j] ) fW2[j,e] + fb2[e]
__global__ __launch_bounds__(128) void gk_h12(const float* __restrict__ xt, const float* __restrict__ xn,
                                              const float* __restrict__ AB, const float* __restrict__ fb1,
                                              const float* __restrict__ fW2, const float* __restrict__ fb2,
                                              float* __restrict__ Hraw) {
  int n = blockIdx.x, e = threadIdx.x;
  long xr = (long)n * DIM + e;
  __shared__ float st[DIM], sn[DIM], h1[DIM];
  st[e] = xt[xr];
  sn[e] = xn[xr];
  __syncthreads();
  float acc = 0.f;
  #pragma unroll 8
  for (int k = 0; k < DIM; ++k)
    acc += st[k] * AB[k * DIM + e] + sn[k] * AB[16384 + k * DIM + e];
  h1[e] = fmaxf(acc + fb1[e], 0.f);
  __syncthreads();
  float acc2 = fb2[e];
  #pragma unroll 8
  for (int j = 0; j < DIM; ++j) acc2 += h1[j] * fW2[(long)j * DIM + e];
  Hraw[(long)n * DIM + e] = acc2;
}

// ---------------------------------------------------------------- reductions
// fused colstats+softmax (one block/column, column register-resident).
// Block 0 also zeroes Gacc (jsd runs strictly after this kernel).
__global__ __launch_bounds__(256) void colsoft_k(const float* __restrict__ Hraw,
                                                 float* __restrict__ HTp, float* __restrict__ Ecol,
                                                 float* __restrict__ Gacc) {
  int e = blockIdx.x;
  int t = threadIdx.x;
  if (e == 0 && t < DIM) Gacc[t] = 0.f;
  __shared__ float sa[4], sb[4], sc[4];
  float v[8];
  float sum = 0.f, sq = 0.f, mx = -3.4e38f;
  #pragma unroll
  for (int r = 0; r < 8; ++r) {
    float x = Hraw[(long)(t + 256 * r) * DIM + e];
    v[r] = x;
    sum += x; sq += x * x; mx = fmaxf(mx, x);
  }
  #pragma unroll
  for (int o = 32; o > 0; o >>= 1) {
    sum += __shfl_down(sum, o);
    sq  += __shfl_down(sq, o);
    mx   = fmaxf(mx, __shfl_down(mx, o));
  }
  if ((t & 63) == 0) { int w = t >> 6; sa[w] = sum; sb[w] = sq; sc[w] = mx; }
  __syncthreads();
  sum = sa[0] + sa[1] + sa[2] + sa[3];
  sq  = sb[0] + sb[1] + sb[2] + sb[3];
  mx  = fmaxf(fmaxf(sc[0], sc[1]), fmaxf(sc[2], sc[3]));
  float mean = sum * (1.f / NTOT);
  float var  = (sq - sum * mean) * (1.f / (NTOT - 1));
  float ia   = 1.f / (sqrtf(fmaxf(var, 0.f)) + 1e-6f);
  float smax = (mx - mean) * ia;
  __syncthreads();

  float den = 0.f;
  #pragma unroll
  for (int r = 0; r < 8; ++r) {
    float s = (v[r] - mean) * ia - smax;
    v[r] = s;
    den += __expf(s);
  }
  #pragma unroll
  for (int o = 32; o > 0; o >>= 1) den += __shfl_down(den, o);
  if ((t & 63) == 0) sa[t >> 6] = den;
  __syncthreads();
  den = sa[0] + sa[1] + sa[2] + sa[3];
  float logden = __logf(den);
  float invden = 1.f / den;
  __syncthreads();

  float ent = 0.f;
  #pragma unroll
  for (int r = 0; r < 8; ++r) {
    float s = v[r];
    float pv = __expf(s) * invden;
    HTp[(long)e * NTOT + t + 256 * r] = pv;
    ent += pv * (s - logden);
  }
  #pragma unroll
  for (int o = 32; o > 0; o >>= 1) ent += __shfl_down(ent, o);
  if ((t & 63) == 0) sa[t >> 6] = ent;
  __syncthreads();
  if (t == 0) Ecol[e] = sa[0] + sa[1] + sa[2] + sa[3];
}

// tiled pairwise-JSD log part: g[i] -= sum_{j!=i} sum_n (a+b)*log((a+b)/2)
__global__ __launch_bounds__(256) void jsd_tile(const float* __restrict__ HTp,
                                                float* __restrict__ g) {
  int b = blockIdx.x;
  int bi = 0, rem = b;
  while (rem >= 8 - bi) { rem -= 8 - bi; ++bi; }
  int bj = bi + rem;                      // bi <= bj
  int n0 = blockIdx.y * (NTOT / JNSPLIT);

  __shared__ float Ti[JT][JNC + 2];
  __shared__ float Tj[JT][JNC + 2];
  __shared__ float red[JT][JT + 1];

  int tid = threadIdx.x;
  int ti = tid >> 4, tj = tid & 15;
  bool active = (bi != bj) || (ti < tj);
  float acc = 0.f;

  int lc = tid >> 4;
  int ln = (tid & 15) * 8;

  for (int c = 0; c < NTOT / JNSPLIT; c += JNC) {
    const float* si = HTp + (long)(bi * JT + lc) * NTOT + n0 + c + ln;
    const float* sj = HTp + (long)(bj * JT + lc) * NTOT + n0 + c + ln;
    #pragma unroll
    for (int r = 0; r < 8; ++r) Ti[lc][ln + r] = si[r];
    #pragma unroll
    for (int r = 0; r < 8; ++r) Tj[lc][ln + r] = sj[r];
    __syncthreads();
    if (active) {
      #pragma unroll 4
      for (int n = 0; n < JNC; ++n) {
        float s = Ti[ti][n] + Tj[tj][n];
        acc += s * __logf(fmaxf(0.5f * s, 1e-38f));
      }
    }
    __syncthreads();
  }

  red[ti][tj] = active ? acc : 0.f;
  __syncthreads();
  if (tid < JT) {
    float s = 0.f;
    #pragma unroll
    for (int j = 0; j < JT; ++j) s += red[tid][j];
    atomicAdd(&g[bi * JT + tid], -s);
  } else if (tid < 2 * JT) {
    int c2 = tid - JT;
    float s = 0.f;
    #pragma unroll
    for (int i = 0; i < JT; ++i) s += red[i][c2];
    atomicAdd(&g[bj * JT + c2], -s);
  }
}

// jm = (g + 126*E + S)/256 -> standardize (ddof=1) -> softmax -> w
__global__ __launch_bounds__(128) void wvec_k(const float* __restrict__ g, const float* __restrict__ Ecol,
                                              float* __restrict__ w) {
  __shared__ float s2[2];
  int t = threadIdx.x;
  float e = Ecol[t];
  float v = e;
  #pragma unroll
  for (int o = 32; o > 0; o >>= 1) v += __shfl_down(v, o);
  if ((t & 63) == 0) s2[t >> 6] = v;
  __syncthreads();
  float S = s2[0] + s2[1];
  __syncthreads();
  float jm = (g[t] + 126.f * e + S) * (1.0f / 256.0f);
  v = jm;
  #pragma unroll
  for (int o = 32; o > 0; o >>= 1) v += __shfl_down(v, o);
  if ((t & 63) == 0) s2[t >> 6] = v;
  __syncthreads();
  float mean = (s2[0] + s2[1]) * (1.0f / 128.0f);
  __syncthreads();
  float d = jm - mean;
  v = d * d;
  #pragma unroll
  for (int o = 32; o > 0; o >>= 1) v += __shfl_down(v, o);
  if ((t & 63) == 0) s2[t >> 6] = v;
  __syncthreads();
  float var = (s2[0] + s2[1]) * (1.0f / 127.0f);
  float njm = d / (sqrtf(var) + 1e-6f);
  __syncthreads();
  v = njm;
  #pragma unroll
  for (int o = 32; o > 0; o >>= 1) v = fmaxf(v, __shfl_down(v, o));
  if ((t & 63) == 0) s2[t >> 6] = v;
  __syncthreads();
  float mx = fmaxf(s2[0], s2[1]);
  float ex = __expf(njm - mx);
  __syncthreads();
  v = ex;
  #pragma unroll
  for (int o = 32; o > 0; o >>= 1) v += __shfl_down(v, o);
  if ((t & 63) == 0) s2[t >> 6] = v;
  __syncthreads();
  w[t] = ex / (s2[0] + s2[1]);
}

// ---------------------------------------------------------------- final chain
// Xzs[bt][split][e][d] = partial sum_n Hsoft[n,e] x[n][d]  (no atomics)
// grid (16, ZSPLIT, 2), block 256
__global__ __launch_bounds__(256) void xz_k(const float* __restrict__ HTp, const float* __restrict__ xt,
                                            const float* __restrict__ xn, float* __restrict__ Xzs) {
  int bt = blockIdx.z;
  const float* x = bt ? xn : xt;
  int split = blockIdx.y;
  float* C = Xzs + ((long)bt * ZSPLIT + split) * 16384;
  int e0 = (blockIdx.x & 3) * 32, d0 = (blockIdx.x >> 2) * 32;
  int n0 = split * (NTOT / ZSPLIT);
  __shared__ float As[32][33], Bs[32][36];   // As[n][e], Bs[n][d]
  int tid = threadIdx.x, col = tid & 31, row = tid >> 5;
  int lr = tid >> 3, lc4 = (tid & 7) * 4;
  int tx = tid & 15, ty = tid >> 4;
  float a00 = 0.f, a01 = 0.f, a10 = 0.f, a11 = 0.f;
  for (int nb = 0; nb < NTOT / ZSPLIT; nb += 32) {
    #pragma unroll
    for (int r = 0; r < 4; ++r) {
      int er = row + r * 8;
      As[col][er] = HTp[(long)(e0 + er) * NTOT + n0 + nb + col];
    }
    *(float4*)&Bs[lr][lc4] = *(const float4*)(x + (long)(n0 + nb + lr) * DIM + d0 + lc4);
    __syncthreads();
    #pragma unroll
    for (int nn = 0; nn < 32; ++nn) {
      float e0v = As[nn][2*ty], e1v = As[nn][2*ty+1];
      float d0v = Bs[nn][2*tx], d1v = Bs[nn][2*tx+1];
      a00 += e0v * d0v; a01 += e0v * d1v;
      a10 += e1v * d0v; a11 += e1v * d1v;
    }
    __syncthreads();
  }
  int e = e0 + 2 * ty, d = d0 + 2 * tx;
  C[e * DIM + d]           = a00;
  C[e * DIM + d + 1]       = a01;
  C[(e + 1) * DIM + d]     = a10;
  C[(e + 1) * DIM + d + 1] = a11;
}

// Zw[bt][e][d] = w[e] * sum_k (sum_s Xzs[bt][s][e][k]) * theta[k][d]   grid (128, 2)
__global__ __launch_bounds__(128) void zs_k(const float* __restrict__ Xzs, const float* __restrict__ thT,
                                            const float* __restrict__ thN, const float* __restrict__ w,
                                            float* __restrict__ Zw) {
  int e = blockIdx.x, d = threadIdx.x, bt = blockIdx.y;
  const float* src = Xzs + (long)bt * ZSPLIT * 16384 + e * DIM + d;
  const float* th = bt ? thN : thT;
  __shared__ float s[DIM];
  float xv = 0.f;
  #pragma unroll
  for (int sp = 0; sp < ZSPLIT; ++sp) xv += src[sp * 16384];
  s[d] = xv;
  __syncthreads();
  float acc = 0.f;
  #pragma unroll 8
  for (int k = 0; k < DIM; ++k) acc += s[k] * th[(long)k * DIM + d];
  Zw[bt * 16384 + e * DIM + d] = acc * w[e];
}

// out[n][d] = x[n][d] + elu( sum_e Hsoft[n,e] Zw[e][d] )  (H read from HTp)
// grid (4, 64, 2), block 256
__global__ __launch_bounds__(256) void uk_t(const float* __restrict__ HTp, const float* __restrict__ Zw,
                                            const float* __restrict__ xt, const float* __restrict__ xn,
                                            float* __restrict__ out) {
  int bt = blockIdx.z;
  const float* x = bt ? xn : xt;
  const float* B = Zw + bt * 16384;
  float* o = out + (long)bt * NTOT * DIM;
  int d0 = blockIdx.x * 32, n0 = blockIdx.y * 32;
  __shared__ float As[32][33], Bs[32][36];   // As[n][e], Bs[e][d]
  int tid = threadIdx.x, col = tid & 31, row = tid >> 5;
  int lr = tid >> 3, lc4 = (tid & 7) * 4;
  int tx = tid & 15, ty = tid >> 4;
  float a00 = 0.f, a01 = 0.f, a10 = 0.f, a11 = 0.f;
  for (int eb = 0; eb < DIM; eb += 32) {
    #pragma unroll
    for (int r = 0; r < 4; ++r) {
      int rr = row + r * 8;
      As[col][rr] = HTp[(long)(eb + rr) * NTOT + n0 + col];   // coalesced along n
    }
    *(float4*)&Bs[lr][lc4] = *(const float4*)(B + (long)(eb + lr) * DIM + d0 + lc4);
    __syncthreads();
    #pragma unroll
    for (int ee = 0; ee < 32; ++ee) {
      float x0 = As[2*ty][ee], x1 = As[2*ty+1][ee];
      float b0 = Bs[ee][2*tx], b1 = Bs[ee][2*tx+1];
      a00 += x0 * b0; a01 += x0 * b1;
      a10 += x1 * b0; a11 += x1 * b1;
    }
    __syncthreads();
  }
  int n = n0 + 2 * ty, d = d0 + 2 * tx;
  long i0 = (long)n * DIM + d, i1 = i0 + DIM;
  float e00 = a00 > 0.f ? a00 : expm1f(a00);
  float e01 = a01 > 0.f ? a01 : expm1f(a01);
  float e10 = a10 > 0.f ? a10 : expm1f(a10);
  float e11 = a11 > 0.f ? a11 : expm1f(a11);
  o[i0]     = x[i0]     + e00;
  o[i0 + 1] = x[i0 + 1] + e01;
  o[i1]     = x[i1]     + e10;
  o[i1 + 1] = x[i1 + 1] + e11;
}

// ---------------------------------------------------------------- launcher
extern "C" void kernel_launch(void* const* d_in, const int* in_sizes, int n_in,
                              void* d_out, int out_size, void* d_ws, size_t ws_size,
                              hipStream_t stream) {
  const float* xt = (const float*)d_in[0];   // x_time (f32 — proven rounds 1/2/10)
  const float* xn = (const float*)d_in[1];   // x_news
  const float *W1[4], *b1[4], *W2[4], *b2[4];
  for (int k = 0; k < 4; ++k) {           // it, inw, t2n, n2t
    W1[k] = (const float*)d_in[2 + 4*k];
    b1[k] = (const float*)d_in[3 + 4*k];
    W2[k] = (const float*)d_in[4 + 4*k];
    b2[k] = (const float*)d_in[5 + 4*k];
  }
  const float* fW1 = (const float*)d_in[18];
  const float* fb1 = (const float*)d_in[19];
  const float* fW2 = (const float*)d_in[20];
  const float* fb2 = (const float*)d_in[21];
  const float* thT = (const float*)d_in[22];
  const float* thN = (const float*)d_in[23];

  // ws map (floats), peak 1377664 = 5.51 MB (no zeroing needed anywhere)
  float* ws    = (float*)d_ws;
  float* Gacc  = ws;                  // [0,128)       zeroed by colsoft block 0
  float* Ecol  = ws + 128;            // [128,256)
  float* Wv    = ws + 256;            // [256,384)
  float* Zw    = ws + 384;            // [384,33152)    (2 batch)
  float* Xzs   = ws + 33152;          // [33152,295296)  2*ZSPLIT*16384 split slabs
  float* Gs    = ws + 295296;         // [295296,819584) 4*MSPLIT*16384 split slabs
  float* Mk    = ws + 819584;         // [819584,885120)
  float* AB    = ws + 885120;         // [885120,917888)
  float* Hraw  = ws + 917888;         // [917888,1180032)
  float* HTp   = ws + 1180032;        // [1180032,1442176)

  float* out = (float*)d_out;         // f32 output, [time | news]

  P4 Xs  = {{xt, xn, xn, xt}};
  P4 W1s = {{W1[0], W1[1], W1[2], W1[3]}};
  P4 B1s = {{b1[0], b1[1], b1[2], b1[3]}};
  P4 W2s = {{W2[0], W2[1], W2[2], W2[3]}};
  P4 B2s = {{b2[0], b2[1], b2[2], b2[3]}};

  gk_mlp1t<<<dim3(16, MSPLIT, 4), 256, 0, stream>>>(Xs, W1s, Gs);
  gk_mlp2<<<dim3(128, 4), 128, 0, stream>>>(Gs, B1s, W2s, B2s, Mk);
  gk_ab  <<<dim3(128, 2), 128, 0, stream>>>(Mk, fW1, AB);
  gk_h12 <<<NTOT, 128, 0, stream>>>(xt, xn, AB, fb1, fW2, fb2, Hraw);

  colsoft_k<<<DIM, 256, 0, stream>>>(Hraw, HTp, Ecol, Gacc);

  jsd_tile<<<dim3(36, JNSPLIT), 256, 0, stream>>>(HTp, Gacc);
  wvec_k<<<1, 128, 0, stream>>>(Gacc, Ecol, Wv);

  // z = (H^T x) theta (reassociated), scaled by w; then out = x + elu(H @ Zw)
  xz_k<<<dim3(16, ZSPLIT, 2), 256, 0, stream>>>(HTp, xt, xn, Xzs);
  zs_k<<<dim3(128, 2), 128, 0, stream>>>(Xzs, thT, thN, Wv, Zw);
  uk_t<<<dim3(4, 64, 2), 256, 0, stream>>>(HTp, Zw, xt, xn, out);

  (void)in_sizes; (void)n_in; (void)out_size; (void)ws_size;
}